// Round 17
// baseline (175.435 us; speedup 1.0000x reference)
//
#include <hip/hip_runtime.h>
#include <math.h>

typedef _Float16 f16x8 __attribute__((ext_vector_type(8)));
typedef float    f32x4 __attribute__((ext_vector_type(4)));

// ---------------------------------------------------------------------------
// Workspace layout:
//   pwd    : [8e][9t][4ks][4nt][64l][8] f16 = 589824  (deconv B, kernel-flipped)
//   pwc    : [8e][9t][2ks][4nt][64l][8] f16 = 294912  (conv2 B, BN folded)
//   pwg_hi : [9t][4ks][8nt][64l][8]     f16 = 147456  (gate B, fp16 hi)
//   pwg_lo : [9t][4ks][8nt][64l][8]     f16 = 147456  (gate B, fp16 residual)
//   pbias  : [8e][64]                   f32 = 512
//   route_i: [1024][2] int
//   route_w: [1024][2] f32
//   pw1t   : [1152][256]                f32 = 294912  (fc1_w transposed)
#define PWD_ELEMS 589824
#define PWC_ELEMS 294912
#define PWG_ELEMS 147456
#define PW1T_ELEMS 294912
#define WS_NEEDED_BYTES ((PWD_ELEMS + PWC_ELEMS + 2 * PWG_ELEMS) * 2 + 512 * 4 + 16384 + PW1T_ELEMS * 4)

__global__ void pack_weights(const float* __restrict__ wd,
                             const float* __restrict__ wc,
                             const float* __restrict__ gw,
                             const float* __restrict__ fc1_w,
                             const float* __restrict__ bc,
                             const float* __restrict__ bn_g,
                             const float* __restrict__ bn_b,
                             const float* __restrict__ bn_m,
                             const float* __restrict__ bn_v,
                             _Float16* __restrict__ pwd,
                             _Float16* __restrict__ pwc,
                             _Float16* __restrict__ pwg_hi,
                             _Float16* __restrict__ pwg_lo,
                             float* __restrict__ pbias,
                             float* __restrict__ pw1t)
{
  int i = blockIdx.x * 256 + threadIdx.x;
  if (i < PWD_ELEMS) {
    int j  = i & 7;
    int l  = (i >> 3) & 63;
    int nt = (i >> 9) & 3;
    int ks = (i >> 11) & 3;
    int rest = i >> 13;            // e*9 + t
    int t = rest % 9, e = rest / 9;
    int ky = t / 3, kx = t % 3;
    int k = ks * 32 + (l >> 4) * 8 + j;   // ci 0..127
    int n = nt * 16 + (l & 15);           // co 0..63
    float v = wd[(((size_t)e * 128 + k) * 64 + n) * 9 + (2 - ky) * 3 + (2 - kx)];
    pwd[i] = (_Float16)v;
    return;
  }
  i -= PWD_ELEMS;
  if (i < PWC_ELEMS) {
    int j  = i & 7;
    int l  = (i >> 3) & 63;
    int nt = (i >> 9) & 3;
    int ks = (i >> 11) & 1;
    int rest = i >> 12;            // e*9 + t
    int t = rest % 9, e = rest / 9;
    int ky = t / 3, kx = t % 3;
    int k = ks * 32 + (l >> 4) * 8 + j;   // ci 0..63
    int n = nt * 16 + (l & 15);           // co 0..63
    float scale = bn_g[e * 64 + n] * rsqrtf(bn_v[e * 64 + n] + 1e-5f);
    float v = wc[(((size_t)e * 64 + n) * 64 + k) * 9 + ky * 3 + kx] * scale;
    pwc[i] = (_Float16)v;
    return;
  }
  i -= PWC_ELEMS;
  if (i < PWG_ELEMS) {
    int j  = i & 7;
    int l  = (i >> 3) & 63;
    int nt = (i >> 9) & 7;
    int ks = (i >> 12) & 3;
    int t  = i >> 14;              // 0..8
    int ky = t / 3, kx = t % 3;
    int k = ks * 32 + (l >> 4) * 8 + j;   // ci 0..127
    int n = nt * 16 + (l & 15);           // co 0..127
    float v = gw[(size_t)n * 1152 + k * 9 + ky * 3 + kx];
    _Float16 hi = (_Float16)v;
    pwg_hi[i] = hi;
    pwg_lo[i] = (_Float16)(v - (float)hi);
    return;
  }
  i -= PWG_ELEMS;
  if (i < 512) {
    int e = i >> 6, n = i & 63;
    float scale = bn_g[e * 64 + n] * rsqrtf(bn_v[e * 64 + n] + 1e-5f);
    pbias[i] = (bc[e * 64 + n] - bn_m[e * 64 + n]) * scale + bn_b[e * 64 + n];
    return;
  }
  i -= 512;
  if (i < PW1T_ELEMS) {
    int k = i >> 8, o = i & 255;          // pw1t[k*256 + o] = fc1_w[o][k]
    pw1t[i] = fc1_w[(size_t)o * 1152 + k];
  }
}

// ---------------------------------------------------------------------------
// Kernel A: gate + routing, two samples per block (unchanged from R13/R15).
__global__ __launch_bounds__(256, 2) void cmoe_gate(
    const float* __restrict__ x, const float* __restrict__ gb,
    const float* __restrict__ pw1t, const float* __restrict__ fc1_b,
    const float* __restrict__ fc2_w, const float* __restrict__ fc2_b,
    const _Float16* __restrict__ pwg_hi, const _Float16* __restrict__ pwg_lo,
    int* __restrict__ route_i, float* __restrict__ route_w)
{
  const int b2 = blockIdx.x;       // sample pair: samples 2*b2, 2*b2+1
  const int tid = threadIdx.x;

  __shared__ __align__(16) char smem[72256];
  _Float16* xg_hi = (_Float16*)smem;               // +s*8704 halfs
  _Float16* xg_lo = (_Float16*)(smem + 34816);     // +s*8704 halfs
  float* zred = (float*)(smem + 44032);            // [2][4][256]
  float* slog = (float*)(smem + 54272);            // [2][8]

  const int w    = tid >> 6;
  const int lane = tid & 63;
  const int lr   = lane & 15;
  const int lq   = lane >> 4;

  // ---- build split-fp16 x with 8x8 halo ring, both samples ----
  for (int idx = tid; idx < 2 * 8192; idx += 256) {
    int s  = idx >> 13;
    int r  = idx & 8191;
    int sp = r >> 7, ci = r & 127;
    int row = sp >> 3, col = sp & 7;
    float v = 0.f;
    if (row >= 1 && row <= 6 && col >= 1 && col <= 6)
      v = x[(size_t)(2 * b2 + s) * 4608 + ci * 36 + (row - 1) * 6 + (col - 1)];
    _Float16 hi = (_Float16)v;
    xg_hi[s * 8704 + sp * 136 + ci] = hi;
    xg_lo[s * 8704 + sp * 136 + ci] = (_Float16)(v - (float)hi);
  }
  __syncthreads();

  int gA[3];
#pragma unroll
  for (int i = 0; i < 3; ++i) {
    int p = i * 16 + lr; if (p >= 36) p = 0;
    int oy = p / 6, ox = p % 6;
    gA[i] = (oy * 8 + ox) * 136 + lq * 8;
  }

  // ---- gate conv3x3, both samples, shared B ----
  {
    f32x4 Cg[2][3][2];
    {
      float b0 = gb[(2 * w) * 16 + lr];
      float b1 = gb[(2 * w + 1) * 16 + lr];
#pragma unroll
      for (int s = 0; s < 2; ++s)
#pragma unroll
        for (int i = 0; i < 3; ++i) {
          Cg[s][i][0] = {b0, b0, b0, b0};
          Cg[s][i][1] = {b1, b1, b1, b1};
        }
    }
    const _Float16* pgh = pwg_hi + lane * 8;
    const _Float16* pgl = pwg_lo + lane * 8;

    for (int t = 0; t < 9; ++t) {
      const int gtap = ((t / 3) * 8 + (t % 3)) * 136;
#pragma unroll
      for (int ks = 0; ks < 4; ++ks) {
        const int boff = ((t * 4 + ks) * 8 + 2 * w) * 512;
        f16x8 Bh0 = *(const f16x8*)(pgh + boff);
        f16x8 Bh1 = *(const f16x8*)(pgh + boff + 512);
        f16x8 Bl0 = *(const f16x8*)(pgl + boff);
        f16x8 Bl1 = *(const f16x8*)(pgl + boff + 512);
#pragma unroll
        for (int s = 0; s < 2; ++s)
#pragma unroll
          for (int i = 0; i < 3; ++i) {
            f16x8 Ah = *(const f16x8*)(xg_hi + s * 8704 + gA[i] + gtap + ks * 32);
            f16x8 Al = *(const f16x8*)(xg_lo + s * 8704 + gA[i] + gtap + ks * 32);
            Cg[s][i][0] = __builtin_amdgcn_mfma_f32_16x16x32_f16(Ah, Bh0, Cg[s][i][0], 0, 0, 0);
            Cg[s][i][1] = __builtin_amdgcn_mfma_f32_16x16x32_f16(Ah, Bh1, Cg[s][i][1], 0, 0, 0);
            Cg[s][i][0] = __builtin_amdgcn_mfma_f32_16x16x32_f16(Al, Bh0, Cg[s][i][0], 0, 0, 0);
            Cg[s][i][1] = __builtin_amdgcn_mfma_f32_16x16x32_f16(Al, Bh1, Cg[s][i][1], 0, 0, 0);
            Cg[s][i][0] = __builtin_amdgcn_mfma_f32_16x16x32_f16(Ah, Bl0, Cg[s][i][0], 0, 0, 0);
            Cg[s][i][1] = __builtin_amdgcn_mfma_f32_16x16x32_f16(Ah, Bl1, Cg[s][i][1], 0, 0, 0);
          }
      }
    }
    __syncthreads();   // all xg_lo reads done; h overlays xlo
#pragma unroll
    for (int s = 0; s < 2; ++s) {
      float* hb = (float*)(smem + 34816 + s * 18432);
#pragma unroll
      for (int i = 0; i < 3; ++i)
#pragma unroll
        for (int nn = 0; nn < 2; ++nn) {
          const int co_ = (2 * w + nn) * 16 + lr;
#pragma unroll
          for (int j = 0; j < 4; ++j) {
            int pix = i * 16 + lq * 4 + j;
            if (pix < 36) hb[co_ * 36 + pix] = fmaxf(Cg[s][i][nn][j], 0.f);
          }
        }
    }
  }
  __syncthreads();

  // ---- maxpool 2x2 (reg-staged over h->p overlay) ----
  {
    float pr[2][5];
#pragma unroll
    for (int r = 0; r < 5; ++r) {
      int i = tid + 256 * r;
      if (i < 1152) {
        int co_ = i / 9, q = i % 9, py = q / 3, px = q % 3;
#pragma unroll
        for (int s = 0; s < 2; ++s) {
          const float* hp = (const float*)(smem + 34816 + s * 18432)
                            + co_ * 36 + (2 * py) * 6 + 2 * px;
          pr[s][r] = fmaxf(fmaxf(hp[0], hp[1]), fmaxf(hp[6], hp[7]));
        }
      }
    }
    __syncthreads();   // all h reads done
#pragma unroll
    for (int r = 0; r < 5; ++r) {
      int i = tid + 256 * r;
      if (i < 1152) {
        ((float*)(smem + 34816))[i] = pr[0][r];
        ((float*)(smem + 39424))[i] = pr[1][r];
      }
    }
  }
  __syncthreads();

  // ---- fc1 (1152 -> 256): phase-split coalesced GEMV, shared weights ----
  {
    const float* pw = pw1t + w * 256 + 4 * lane;
    const float* p0 = (const float*)(smem + 34816);
    const float* p1 = (const float*)(smem + 39424);
    f32x4 a0 = {0.f, 0.f, 0.f, 0.f}, a1 = {0.f, 0.f, 0.f, 0.f};
#pragma unroll 4
    for (int m = 0; m < 288; ++m) {
      float pv0 = p0[w + 4 * m];                    // wave-uniform broadcast
      float pv1 = p1[w + 4 * m];
      f32x4 wv = *(const f32x4*)(pw + m * 1024);    // coalesced, shared
      a0.x += wv.x * pv0; a0.y += wv.y * pv0; a0.z += wv.z * pv0; a0.w += wv.w * pv0;
      a1.x += wv.x * pv1; a1.y += wv.y * pv1; a1.z += wv.z * pv1; a1.w += wv.w * pv1;
    }
    *(f32x4*)&zred[(0 * 4 + w) * 256 + 4 * lane] = a0;
    *(f32x4*)&zred[(1 * 4 + w) * 256 + 4 * lane] = a1;
  }
  __syncthreads();
  float* z0 = (float*)(smem + 52224);
  float* z1 = (float*)(smem + 53248);
  {
    float fb = fc1_b[tid];
    z0[tid] = fmaxf(zred[tid] + zred[256 + tid] + zred[512 + tid] + zred[768 + tid] + fb, 0.f);
    z1[tid] = fmaxf(zred[1024 + tid] + zred[1280 + tid] + zred[1536 + tid] + zred[1792 + tid] + fb, 0.f);
  }
  __syncthreads();

  // ---- fc2 (256 -> 8), wave-parallel, both samples ----
  if (tid < 128) {
    int s = tid >> 6, l = tid & 63;
    int o = l >> 3, t8 = l & 7;
    const float* zz = s ? z1 : z0;
    const float* wr = fc2_w + o * 256;
    float acc = 0.f;
    for (int k = t8; k < 256; k += 8) acc += zz[k] * wr[k];
    acc += __shfl_xor(acc, 1);
    acc += __shfl_xor(acc, 2);
    acc += __shfl_xor(acc, 4);
    if (t8 == 0) slog[s * 8 + o] = acc + fc2_b[o];
  }
  __syncthreads();

  // ---- top-2 + softmax -> route table (both samples) ----
  if (tid == 0) {
#pragma unroll
    for (int s = 0; s < 2; ++s) {
      const float* sl = slog + s * 8;
      int i0 = 0; float v0 = sl[0];
#pragma unroll
      for (int o = 1; o < 8; ++o) { float v = sl[o]; if (v > v0) { v0 = v; i0 = o; } }
      int i1 = (i0 == 0) ? 1 : 0; float v1 = sl[i1];
#pragma unroll
      for (int o = 0; o < 8; ++o) {
        if (o != i0) { float v = sl[o]; if (v > v1) { v1 = v; i1 = o; } }
      }
      float e1 = expf(v1 - v0);
      float inv = 1.f / (1.f + e1);
      int sb = 2 * b2 + s;
      route_i[2 * sb] = i0; route_i[2 * sb + 1] = i1;
      route_w[2 * sb] = inv; route_w[2 * sb + 1] = e1 * inv;
    }
  }
}

// ---------------------------------------------------------------------------
// Kernel B: experts. R15 structure (RMW out, no facc — least spill, fastest
// measured) + R8-verified 16B-chunk XOR swizzle on x: x stored [36][128] with
// chunk ^= (pix&7); deconv reads XOR the same key. Kills the 8-way conflict
// on deconv A-reads (40% of expert LDS reads) while keeping ds_read_b128
// alignment (R14's +pad broke alignment and regressed 3x). y1 untouched.
#define ZOFF  4608
#define Y1OFF 4736

#define DECONV_TAP(KY, KX)                                                  \
  {                                                                         \
    constexpr int t_  = (KY) * 3 + (KX);                                    \
    constexpr int dy_ = ((KY) == 2) ? 1 : 0;                                \
    constexpr int dx_ = ((KX) == 2) ? 1 : 0;                                \
    int u0 = uA[0] + dy_, v0 = vA[0] + dx_;                                 \
    int u1 = uA[1] + dy_, v1 = vA[1] + dx_;                                 \
    int u2 = uA[2] + dy_, v2 = vA[2] + dx_;                                 \
    bool g0 = pvA[0] && u0 < 6 && v0 < 6;                                   \
    bool g1 = pvA[1] && u1 < 6 && v1 < 6;                                   \
    bool g2 = pvA[2] && u2 < 6 && v2 < 6;                                   \
    int r0 = u0 * 6 + v0, r1 = u1 * 6 + v1, r2 = u2 * 6 + v2;               \
    int b0_ = g0 ? r0 * 128 : ZOFF;                                         \
    int b1_ = g1 ? r1 * 128 : ZOFF;                                         \
    int b2_ = g2 ? r2 * 128 : ZOFF;                                         \
    int k0_ = g0 ? (r0 & 7) : 0;                                            \
    int k1_ = g1 ? (r1 & 7) : 0;                                            \
    int k2_ = g2 ? (r2 & 7) : 0;                                            \
    _Pragma("unroll")                                                       \
    for (int ks = 0; ks < 4; ++ks) {                                        \
      f16x8 Bf = *(const f16x8*)(pwd_e + (size_t)(t_ * 4 + ks) * 2048);     \
      f16x8 A0 = *(const f16x8*)(S + b0_ + (((lq + 4 * ks) ^ k0_) << 3));   \
      f16x8 A1 = *(const f16x8*)(S + b1_ + (((lq + 4 * ks) ^ k1_) << 3));   \
      f16x8 A2 = *(const f16x8*)(S + b2_ + (((lq + 4 * ks) ^ k2_) << 3));   \
      Cd0 = __builtin_amdgcn_mfma_f32_16x16x32_f16(A0, Bf, Cd0, 0, 0, 0);   \
      Cd1 = __builtin_amdgcn_mfma_f32_16x16x32_f16(A1, Bf, Cd1, 0, 0, 0);   \
      Cd2 = __builtin_amdgcn_mfma_f32_16x16x32_f16(A2, Bf, Cd2, 0, 0, 0);   \
    }                                                                       \
  }

#define STORE_CLASS(QY, QX)                                                 \
  _Pragma("unroll")                                                         \
  for (int i = 0; i < 3; ++i) {                                             \
    f32x4 Cv = (i == 0) ? Cd0 : ((i == 1) ? Cd1 : Cd2);                     \
    _Pragma("unroll")                                                       \
    for (int j = 0; j < 4; ++j) {                                           \
      int p = i * 16 + lq * 4 + j;                                          \
      if (p < 36) {                                                         \
        int u = p / 6, v = p - 6 * (p / 6);                                 \
        int oy = 2 * u + (QY), ox = 2 * v + (QX);                           \
        S[Y1OFF + ((oy + 1) * 14 + (ox + 1)) * 72 + co] =                   \
            (_Float16)fmaxf(Cv[j], 0.f);                                    \
      }                                                                     \
    }                                                                       \
  }

__global__ __launch_bounds__(256, 4) void cmoe_expert(
    const float* __restrict__ x,
    const float* __restrict__ bd,
    const _Float16* __restrict__ pwd, const _Float16* __restrict__ pwc,
    const float* __restrict__ pbias,
    const int* __restrict__ route_i, const float* __restrict__ route_w,
    float* __restrict__ out)
{
  const int b = blockIdx.x;
  const int tid = threadIdx.x;

  __shared__ __align__(16) char smem[37696];
  _Float16* S = (_Float16*)smem;
  float* sout = (float*)(smem + 9472);   // [72][65] f32, overlays y1

  const int w    = tid >> 6;
  const int lane = tid & 63;
  const int lr   = lane & 15;
  const int lq   = lane >> 4;

  const int e0 = route_i[2 * b], e1 = route_i[2 * b + 1];
  const float w0 = route_w[2 * b], w1 = route_w[2 * b + 1];

  // ---- stage x [36][128] f16, XOR-swizzled (R8-verified) + zero block ----
  const float* xb = x + (size_t)b * 4608;
  for (int idx = tid; idx < 4608; idx += 256) {
    int ci = idx / 36, pix = idx - ci * 36;
    int sci = ci ^ ((pix & 7) << 3);
    S[pix * 128 + sci] = (_Float16)xb[idx];
  }
  if (tid < 128) S[ZOFF + tid] = (_Float16)0.f;

  const int co = w * 16 + lr;

  int uA[3], vA[3], pvA[3];
#pragma unroll
  for (int i = 0; i < 3; ++i) {
    int p = i * 16 + lr;
    pvA[i] = (p < 36);
    int pc = pvA[i] ? p : 0;
    uA[i] = pc / 6; vA[i] = pc - 6 * (pc / 6);
  }
  int cA[9];
#pragma unroll
  for (int mt = 0; mt < 9; ++mt) {
    int pix = mt * 16 + lr;
    int oy = pix / 12, ox = pix - 12 * (pix / 12);
    cA[mt] = Y1OFF + (oy * 14 + ox) * 72 + lq * 8;
  }

  float* ob = out + (size_t)b * 9216;

#pragma unroll 1
  for (int s = 0; s < 2; ++s) {
    const int e = s ? e1 : e0;
    const float wgt = s ? w1 : w0;
    const float db = bd[e * 64 + co];
    const _Float16* pwd_e = pwd + (size_t)e * (9 * 4 * 4 * 512) + w * 512 + lane * 8;

    __syncthreads();   // s=0: x staged; s=1: prev slot's sout reads done

    // ---- y1 zero ring (y1 region overlapped prev sout; safe after barrier) ----
    for (int idx = tid; idx < 52 * 72; idx += 256) {
      int sp = idx / 72, ci = idx % 72;
      int row, col;
      if (sp < 14)      { row = 0;       col = sp; }
      else if (sp < 28) { row = 13;      col = sp - 14; }
      else if (sp < 40) { row = sp - 27; col = 0; }
      else              { row = sp - 39; col = 13; }
      S[Y1OFF + (row * 14 + col) * 72 + ci] = (_Float16)0.f;
    }

    // ---- deconv (parity classes, named regs, swizzled x reads) ----
    {  // class (qy=1,qx=1)
      f32x4 Cd0 = {db, db, db, db}, Cd1 = Cd0, Cd2 = Cd0;
      DECONV_TAP(0, 0) DECONV_TAP(0, 2) DECONV_TAP(2, 0) DECONV_TAP(2, 2)
      STORE_CLASS(1, 1)
    }
    {  // class (qy=1,qx=0)
      f32x4 Cd0 = {db, db, db, db}, Cd1 = Cd0, Cd2 = Cd0;
      DECONV_TAP(0, 1) DECONV_TAP(2, 1)
      STORE_CLASS(1, 0)
    }
    {  // class (qy=0,qx=1)
      f32x4 Cd0 = {db, db, db, db}, Cd1 = Cd0, Cd2 = Cd0;
      DECONV_TAP(1, 0) DECONV_TAP(1, 2)
      STORE_CLASS(0, 1)
    }
    {  // class (qy=0,qx=0)
      f32x4 Cd0 = {db, db, db, db}, Cd1 = Cd0, Cd2 = Cd0;
      DECONV_TAP(1, 1)
      STORE_CLASS(0, 0)
    }
    __syncthreads();   // y1 complete (ring + data)

    // ---- conv2 (9 tap-GEMMs, K=64), BN folded; scale by wgt in place ----
    f32x4 Cc[9];
    {
      const float cb = pbias[e * 64 + co];
#pragma unroll
      for (int mt = 0; mt < 9; ++mt) Cc[mt] = {cb, cb, cb, cb};
    }
    const _Float16* pwc_e = pwc + (size_t)e * (9 * 2 * 4 * 512) + w * 512 + lane * 8;

#pragma unroll
    for (int t = 0; t < 9; ++t) {
      const int ky = t / 3, kx = t % 3;
      const int aoff = (ky * 14 + kx) * 72;
#pragma unroll
      for (int ks = 0; ks < 2; ++ks) {
        f16x8 Bf = *(const f16x8*)(pwc_e + (size_t)(t * 2 + ks) * 2048);
#pragma unroll
        for (int mt = 0; mt < 9; ++mt) {
          f16x8 Af = *(const f16x8*)(S + cA[mt] + aoff + ks * 32);
          Cc[mt] = __builtin_amdgcn_mfma_f32_16x16x32_f16(Af, Bf, Cc[mt], 0, 0, 0);
        }
      }
    }
#pragma unroll
    for (int mt = 0; mt < 9; ++mt)
#pragma unroll
      for (int j = 0; j < 4; ++j)
        Cc[mt][j] = wgt * fmaxf(Cc[mt][j], 0.f);

    // ---- 2-pass transpose-stage; slot0 stores, slot1 RMW-adds ----
    __syncthreads();   // conv2 y1 reads done; sout overlays y1
#pragma unroll
    for (int mt = 0; mt < 9; ++mt)
#pragma unroll
      for (int j = 0; j < 4; ++j) {
        int pix = mt * 16 + lq * 4 + j;
        if (pix < 72) sout[pix * 65 + co] = Cc[mt][j];
      }
    __syncthreads();
    if (s == 0) {
      for (int j2 = tid; j2 < 4608; j2 += 256) {
        int c2 = j2 / 72, px = j2 - 72 * c2;
        ob[c2 * 144 + px] = sout[px * 65 + c2];
      }
    } else {
      for (int j2 = tid; j2 < 4608; j2 += 256) {
        int c2 = j2 / 72, px = j2 - 72 * c2;
        ob[c2 * 144 + px] += sout[px * 65 + c2];
      }
    }
    __syncthreads();   // sout reads done; restage second half
#pragma unroll
    for (int mt = 0; mt < 9; ++mt)
#pragma unroll
      for (int j = 0; j < 4; ++j) {
        int pix = mt * 16 + lq * 4 + j;
        if (pix >= 72) sout[(pix - 72) * 65 + co] = Cc[mt][j];
      }
    __syncthreads();
    if (s == 0) {
      for (int j2 = tid; j2 < 4608; j2 += 256) {
        int c2 = j2 / 72, px = j2 - 72 * c2;
        ob[c2 * 144 + 72 + px] = sout[px * 65 + c2];
      }
    } else {
      for (int j2 = tid; j2 < 4608; j2 += 256) {
        int c2 = j2 / 72, px = j2 - 72 * c2;
        ob[c2 * 144 + 72 + px] += sout[px * 65 + c2];
      }
    }
    // loop-top barrier orders these sout reads vs next slot's ring writes
  }
}

// ---------------------------------------------------------------------------
// FALLBACK kernel (R1, fp32, known-good) — used when ws_size is too small.

#define DECONV_TAPS(q, ky, r)                                              \
  _Pragma("unroll")                                                        \
  for (int ox = 0; ox < 12; ++ox) {                                        \
    _Pragma("unroll")                                                      \
    for (int kx = 0; kx < 3; ++kx) {                                       \
      const int ss = ox + kx - 1;                                          \
      if (ss >= 0 && ss <= 10 && (ss & 1) == 0)                            \
        dacc[q][ox] += xr[r][ss >> 1] * w9[8 - ((ky) * 3 + (kx))];         \
    }                                                                      \
  }

__global__ __launch_bounds__(256, 2) void cmoe_ref(
    const float* __restrict__ x,
    const float* __restrict__ gw, const float* __restrict__ gb,
    const float* __restrict__ fc1_w, const float* __restrict__ fc1_b,
    const float* __restrict__ fc2_w, const float* __restrict__ fc2_b,
    const float* __restrict__ wd, const float* __restrict__ bd,
    const float* __restrict__ wc, const float* __restrict__ bc,
    const float* __restrict__ bn_g, const float* __restrict__ bn_b,
    const float* __restrict__ bn_m, const float* __restrict__ bn_v,
    float* __restrict__ out)
{
  const int b = blockIdx.x;
  const int tid = threadIdx.x;

  __shared__ float sx[128 * 48];
  __shared__ float sbuf[64 * 168];
  __shared__ int   se[2];
  __shared__ float swv[2];

  const float* xb = x + (size_t)b * 4608;
  for (int i = tid; i < 4608; i += 256) {
    int ci = i / 36, rem = i % 36;
    sx[ci * 48 + 6 + rem] = xb[i];
  }
  for (int i = tid; i < 128 * 12; i += 256) {
    int ci = i / 12, j = i % 12;
    sx[ci * 48 + (j < 6 ? j : 36 + j)] = 0.f;
  }
  __syncthreads();

  {
    const int co = tid >> 1;
    const int hh = tid & 1;
    float hacc[3][6];
    const float bias = gb[co];
#pragma unroll
    for (int q = 0; q < 3; ++q)
#pragma unroll
      for (int ox = 0; ox < 6; ++ox) hacc[q][ox] = bias;

    const float* wbase = gw + co * 1152;
    const float* xsb = sx + hh * 18;
    for (int ci = 0; ci < 128; ++ci) {
      const float* wr = wbase + ci * 9;
      float w9[9];
#pragma unroll
      for (int k = 0; k < 9; ++k) w9[k] = wr[k];
      const float* xr = xsb + ci * 48;
#pragma unroll
      for (int s = 0; s < 5; ++s) {
        float r8[8];
        r8[0] = 0.f; r8[7] = 0.f;
#pragma unroll
        for (int c = 0; c < 6; ++c) r8[c + 1] = xr[s * 6 + c];
#pragma unroll
        for (int ky = 0; ky < 3; ++ky) {
          const int q = s - ky;
          if (q >= 0 && q < 3) {
#pragma unroll
            for (int ox = 0; ox < 6; ++ox)
#pragma unroll
              for (int kx = 0; kx < 3; ++kx)
                hacc[q][ox] += r8[ox + kx] * w9[ky * 3 + kx];
          }
        }
      }
    }
#pragma unroll
    for (int q = 0; q < 3; ++q)
#pragma unroll
      for (int ox = 0; ox < 6; ++ox)
        sbuf[co * 36 + (3 * hh + q) * 6 + ox] = fmaxf(hacc[q][ox], 0.f);
  }
  __syncthreads();

  {
    float* sp = sbuf + 4608;
    for (int i = tid; i < 1152; i += 256) {
      int co = i / 9, r = i % 9, py = r / 3, px = r % 3;
      const float* hp = sbuf + co * 36 + (2 * py) * 6 + 2 * px;
      sp[i] = fmaxf(fmaxf(hp[0], hp[1]), fmaxf(hp[6], hp[7]));
    }
  }
  __syncthreads();

  {
    const float* sp = sbuf + 4608;
    float* sz = sbuf + 5760;
    float acc = fc1_b[tid];
    const float4* wr = (const float4*)(fc1_w + (size_t)tid * 1152);
    const float4* p4 = (const float4*)sp;
#pragma unroll 4
    for (int k = 0; k < 288; ++k) {
      float4 wv4 = wr[k], pv = p4[k];
      acc += wv4.x * pv.x + wv4.y * pv.y + wv4.z * pv.z + wv4.w * pv.w;
    }
    sz[tid] = fmaxf(acc, 0.f);
  }
  __syncthreads();

  {
    const float* sz = sbuf + 5760;
    float* slog = sbuf + 6016;
    if (tid < 8) {
      float acc = fc2_b[tid];
      const float* wr = fc2_w + tid * 256;
      for (int k = 0; k < 256; ++k) acc += sz[k] * wr[k];
      slog[tid] = acc;
    }
  }
  __syncthreads();

  if (tid == 0) {
    const float* slog = sbuf + 6016;
    int i0 = 0; float v0 = slog[0];
#pragma unroll
    for (int o = 1; o < 8; ++o) { float v = slog[o]; if (v > v0) { v0 = v; i0 = o; } }
    int i1 = (i0 == 0) ? 1 : 0; float v1 = slog[i1];
#pragma unroll
    for (int o = 0; o < 8; ++o) {
      if (o != i0) { float v = slog[o]; if (v > v1) { v1 = v; i1 = o; } }
    }
    float e1 = expf(v1 - v0);
    float inv = 1.f / (1.f + e1);
    se[0] = i0; se[1] = i1; swv[0] = inv; swv[1] = e1 * inv;
  }
  __syncthreads();

  for (int i = tid; i < 64 * 24; i += 256) {
    int ci = i / 24, j = i % 24;
    sbuf[ci * 168 + (j < 12 ? j : 144 + j)] = 0.f;
  }

  const int wv = tid >> 6;
  const int co = tid & 63;
  const int iyb = (wv & 1) ? (3 * wv - 1) / 2 : (3 * wv) / 2;

  float facc[3][12];
#pragma unroll
  for (int q = 0; q < 3; ++q)
#pragma unroll
    for (int ox = 0; ox < 12; ++ox) facc[q][ox] = 0.f;

  for (int slot = 0; slot < 2; ++slot) {
    const int e = se[slot];
    const float wgt = swv[slot];

    float dacc[3][12];
    {
      const float db = bd[e * 64 + co];
#pragma unroll
      for (int q = 0; q < 3; ++q)
#pragma unroll
        for (int ox = 0; ox < 12; ++ox) dacc[q][ox] = db;

      const float* wdb = wd + ((size_t)e * 128 * 64 + co) * 9;
      for (int ci = 0; ci < 128; ++ci) {
        const float* wr = wdb + (size_t)ci * 576;
        float w9[9];
#pragma unroll
        for (int k = 0; k < 9; ++k) w9[k] = wr[k];
        float xr[3][6];
#pragma unroll
        for (int r = 0; r < 3; ++r)
#pragma unroll
          for (int c = 0; c < 6; ++c)
            xr[r][c] = sx[ci * 48 + (iyb + r + 1) * 6 + c];
        if (wv & 1) {
          DECONV_TAPS(0, 0, 0)
          DECONV_TAPS(0, 2, 1)
          DECONV_TAPS(1, 1, 1)
          DECONV_TAPS(2, 0, 1)
          DECONV_TAPS(2, 2, 2)
        } else {
          DECONV_TAPS(0, 1, 0)
          DECONV_TAPS(1, 0, 0)
          DECONV_TAPS(1, 2, 1)
          DECONV_TAPS(2, 1, 1)
        }
      }
    }

    __syncthreads();
#pragma unroll
    for (int q = 0; q < 3; ++q)
#pragma unroll
      for (int ox = 0; ox < 12; ++ox)
        sbuf[co * 168 + (3 * wv + q + 1) * 12 + ox] = fmaxf(dacc[q][ox], 0.f);
    __syncthreads();

    float cacc[3][12];
    const float cb = bc[e * 64 + co];
#pragma unroll
    for (int q = 0; q < 3; ++q)
#pragma unroll
      for (int ox = 0; ox < 12; ++ox) cacc[q][ox] = cb;

    const float* wcb = wc + ((size_t)e * 64 + co) * 576;
    for (int ci = 0; ci < 64; ++ci) {
      const float* wr = wcb + ci * 9;
      float w9[9];
#pragma unroll
      for (int k = 0; k < 9; ++k) w9[k] = wr[k];
#pragma unroll
      for (int s = 0; s < 5; ++s) {
        float r14[14];
        r14[0] = 0.f; r14[13] = 0.f;
#pragma unroll
        for (int c = 0; c < 12; ++c) r14[c + 1] = sbuf[ci * 168 + (3 * wv + s) * 12 + c];
#pragma unroll
        for (int ky = 0; ky < 3; ++ky) {
          const int q = s - ky;
          if (q >= 0 && q < 3) {
#pragma unroll
            for (int ox = 0; ox < 12; ++ox)
#pragma unroll
              for (int kx = 0; kx < 3; ++kx)
                cacc[q][ox] += r14[ox + kx] * w9[ky * 3 + kx];
          }
        }
      }
    }

    const float g = bn_g[e * 64 + co], bb = bn_b[e * 64 + co];
    const float mm = bn_m[e * 64 + co], vvv = bn_v[e * 64 + co];
    const float scale = g * rsqrtf(vvv + 1e-5f);
#pragma unroll
    for (int q = 0; q < 3; ++q)
#pragma unroll
      for (int ox = 0; ox < 12; ++ox) {
        float v = (cacc[q][ox] - mm) * scale + bb;
        facc[q][ox] += wgt * fmaxf(v, 0.f);
      }
  }

  float* ob = out + ((size_t)b * 64 + co) * 144;
#pragma unroll
  for (int q = 0; q < 3; ++q)
#pragma unroll
    for (int ox = 0; ox < 12; ++ox)
      ob[(3 * wv + q) * 12 + ox] = facc[q][ox];
}

extern "C" void kernel_launch(void* const* d_in, const int* in_sizes, int n_in,
                              void* d_out, int out_size, void* d_ws, size_t ws_size,
                              hipStream_t stream) {
  const float* x     = (const float*)d_in[0];
  const float* gw    = (const float*)d_in[1];
  const float* gb    = (const float*)d_in[2];
  const float* fc1_w = (const float*)d_in[3];
  const float* fc1_b = (const float*)d_in[4];
  const float* fc2_w = (const float*)d_in[5];
  const float* fc2_b = (const float*)d_in[6];
  const float* wd    = (const float*)d_in[7];
  const float* bd    = (const float*)d_in[8];
  const float* wc    = (const float*)d_in[9];
  const float* bc    = (const float*)d_in[10];
  const float* bn_g  = (const float*)d_in[11];
  const float* bn_b  = (const float*)d_in[12];
  const float* bn_m  = (const float*)d_in[13];
  const float* bn_v  = (const float*)d_in[14];
  float* out = (float*)d_out;

  if (ws_size >= (size_t)WS_NEEDED_BYTES && d_ws != nullptr) {
    _Float16* pwd    = (_Float16*)d_ws;
    _Float16* pwc    = pwd + PWD_ELEMS;
    _Float16* pwg_hi = pwc + PWC_ELEMS;
    _Float16* pwg_lo = pwg_hi + PWG_ELEMS;
    float*    pbias  = (float*)(pwg_lo + PWG_ELEMS);
    int*      route_i = (int*)(pbias + 512);
    float*    route_w = (float*)(route_i + 2048);
    float*    pw1t   = route_w + 2048;

    int total = PWD_ELEMS + PWC_ELEMS + PWG_ELEMS + 512 + PW1T_ELEMS;
    pack_weights<<<dim3((total + 255) / 256), dim3(256), 0, stream>>>(
        wd, wc, gw, fc1_w, bc, bn_g, bn_b, bn_m, bn_v,
        pwd, pwc, pwg_hi, pwg_lo, pbias, pw1t);
    cmoe_gate<<<dim3(512), dim3(256), 0, stream>>>(
        x, gb, pw1t, fc1_b, fc2_w, fc2_b, pwg_hi, pwg_lo, route_i, route_w);
    cmoe_expert<<<dim3(1024), dim3(256), 0, stream>>>(
        x, bd, pwd, pwc, pbias, route_i, route_w, out);
  } else {
    cmoe_ref<<<dim3(1024), dim3(256), 0, stream>>>(
        x, gw, gb, fc1_w, fc1_b, fc2_w, fc2_b,
        wd, bd, wc, bc, bn_g, bn_b, bn_m, bn_v, out);
  }
}

// Round 18
// 155.675 us; speedup vs baseline: 1.1269x; 1.1269x over previous
//
#include <hip/hip_runtime.h>
#include <math.h>

typedef _Float16 f16x8 __attribute__((ext_vector_type(8)));
typedef float    f32x4 __attribute__((ext_vector_type(4)));

// ---------------------------------------------------------------------------
// Workspace layout:
//   pwd    : [8e][9t][4ks][4nt][64l][8] f16 = 589824  (deconv B, kernel-flipped)
//   pwc    : [8e][9t][2ks][4nt][64l][8] f16 = 294912  (conv2 B, BN folded)
//   pwg_hi : [9t][4ks][8nt][64l][8]     f16 = 147456  (gate B, fp16 hi)
//   pwg_lo : [9t][4ks][8nt][64l][8]     f16 = 147456  (gate B, fp16 residual)
//   pbias  : [8e][64]                   f32 = 512
//   route_i: [1024][2] int
//   route_w: [1024][2] f32
//   pw1t   : [1152][256]                f32 = 294912  (fc1_w transposed)
#define PWD_ELEMS 589824
#define PWC_ELEMS 294912
#define PWG_ELEMS 147456
#define PW1T_ELEMS 294912
#define WS_NEEDED_BYTES ((PWD_ELEMS + PWC_ELEMS + 2 * PWG_ELEMS) * 2 + 512 * 4 + 16384 + PW1T_ELEMS * 4)

__global__ void pack_weights(const float* __restrict__ wd,
                             const float* __restrict__ wc,
                             const float* __restrict__ gw,
                             const float* __restrict__ fc1_w,
                             const float* __restrict__ bc,
                             const float* __restrict__ bn_g,
                             const float* __restrict__ bn_b,
                             const float* __restrict__ bn_m,
                             const float* __restrict__ bn_v,
                             _Float16* __restrict__ pwd,
                             _Float16* __restrict__ pwc,
                             _Float16* __restrict__ pwg_hi,
                             _Float16* __restrict__ pwg_lo,
                             float* __restrict__ pbias,
                             float* __restrict__ pw1t)
{
  int i = blockIdx.x * 256 + threadIdx.x;
  if (i < PWD_ELEMS) {
    int j  = i & 7;
    int l  = (i >> 3) & 63;
    int nt = (i >> 9) & 3;
    int ks = (i >> 11) & 3;
    int rest = i >> 13;            // e*9 + t
    int t = rest % 9, e = rest / 9;
    int ky = t / 3, kx = t % 3;
    int k = ks * 32 + (l >> 4) * 8 + j;   // ci 0..127
    int n = nt * 16 + (l & 15);           // co 0..63
    float v = wd[(((size_t)e * 128 + k) * 64 + n) * 9 + (2 - ky) * 3 + (2 - kx)];
    pwd[i] = (_Float16)v;
    return;
  }
  i -= PWD_ELEMS;
  if (i < PWC_ELEMS) {
    int j  = i & 7;
    int l  = (i >> 3) & 63;
    int nt = (i >> 9) & 3;
    int ks = (i >> 11) & 1;
    int rest = i >> 12;            // e*9 + t
    int t = rest % 9, e = rest / 9;
    int ky = t / 3, kx = t % 3;
    int k = ks * 32 + (l >> 4) * 8 + j;   // ci 0..63
    int n = nt * 16 + (l & 15);           // co 0..63
    float scale = bn_g[e * 64 + n] * rsqrtf(bn_v[e * 64 + n] + 1e-5f);
    float v = wc[(((size_t)e * 64 + n) * 64 + k) * 9 + ky * 3 + kx] * scale;
    pwc[i] = (_Float16)v;
    return;
  }
  i -= PWC_ELEMS;
  if (i < PWG_ELEMS) {
    int j  = i & 7;
    int l  = (i >> 3) & 63;
    int nt = (i >> 9) & 7;
    int ks = (i >> 12) & 3;
    int t  = i >> 14;              // 0..8
    int ky = t / 3, kx = t % 3;
    int k = ks * 32 + (l >> 4) * 8 + j;   // ci 0..127
    int n = nt * 16 + (l & 15);           // co 0..127
    float v = gw[(size_t)n * 1152 + k * 9 + ky * 3 + kx];
    _Float16 hi = (_Float16)v;
    pwg_hi[i] = hi;
    pwg_lo[i] = (_Float16)(v - (float)hi);
    return;
  }
  i -= PWG_ELEMS;
  if (i < 512) {
    int e = i >> 6, n = i & 63;
    float scale = bn_g[e * 64 + n] * rsqrtf(bn_v[e * 64 + n] + 1e-5f);
    pbias[i] = (bc[e * 64 + n] - bn_m[e * 64 + n]) * scale + bn_b[e * 64 + n];
    return;
  }
  i -= 512;
  if (i < PW1T_ELEMS) {
    int k = i >> 8, o = i & 255;          // pw1t[k*256 + o] = fc1_w[o][k]
    pw1t[i] = fc1_w[(size_t)o * 1152 + k];
  }
}

// ---------------------------------------------------------------------------
// Kernel A: gate + routing, two samples per block (R13-verified).
__global__ __launch_bounds__(256, 2) void cmoe_gate(
    const float* __restrict__ x, const float* __restrict__ gb,
    const float* __restrict__ pw1t, const float* __restrict__ fc1_b,
    const float* __restrict__ fc2_w, const float* __restrict__ fc2_b,
    const _Float16* __restrict__ pwg_hi, const _Float16* __restrict__ pwg_lo,
    int* __restrict__ route_i, float* __restrict__ route_w)
{
  const int b2 = blockIdx.x;       // sample pair: samples 2*b2, 2*b2+1
  const int tid = threadIdx.x;

  __shared__ __align__(16) char smem[72256];
  _Float16* xg_hi = (_Float16*)smem;               // +s*8704 halfs
  _Float16* xg_lo = (_Float16*)(smem + 34816);     // +s*8704 halfs
  float* zred = (float*)(smem + 44032);            // [2][4][256]
  float* slog = (float*)(smem + 54272);            // [2][8]

  const int w    = tid >> 6;
  const int lane = tid & 63;
  const int lr   = lane & 15;
  const int lq   = lane >> 4;

  // ---- build split-fp16 x with 8x8 halo ring, both samples ----
  for (int idx = tid; idx < 2 * 8192; idx += 256) {
    int s  = idx >> 13;
    int r  = idx & 8191;
    int sp = r >> 7, ci = r & 127;
    int row = sp >> 3, col = sp & 7;
    float v = 0.f;
    if (row >= 1 && row <= 6 && col >= 1 && col <= 6)
      v = x[(size_t)(2 * b2 + s) * 4608 + ci * 36 + (row - 1) * 6 + (col - 1)];
    _Float16 hi = (_Float16)v;
    xg_hi[s * 8704 + sp * 136 + ci] = hi;
    xg_lo[s * 8704 + sp * 136 + ci] = (_Float16)(v - (float)hi);
  }
  __syncthreads();

  int gA[3];
#pragma unroll
  for (int i = 0; i < 3; ++i) {
    int p = i * 16 + lr; if (p >= 36) p = 0;
    int oy = p / 6, ox = p % 6;
    gA[i] = (oy * 8 + ox) * 136 + lq * 8;
  }

  // ---- gate conv3x3, both samples, shared B ----
  {
    f32x4 Cg[2][3][2];
    {
      float b0 = gb[(2 * w) * 16 + lr];
      float b1 = gb[(2 * w + 1) * 16 + lr];
#pragma unroll
      for (int s = 0; s < 2; ++s)
#pragma unroll
        for (int i = 0; i < 3; ++i) {
          Cg[s][i][0] = {b0, b0, b0, b0};
          Cg[s][i][1] = {b1, b1, b1, b1};
        }
    }
    const _Float16* pgh = pwg_hi + lane * 8;
    const _Float16* pgl = pwg_lo + lane * 8;

    for (int t = 0; t < 9; ++t) {
      const int gtap = ((t / 3) * 8 + (t % 3)) * 136;
#pragma unroll
      for (int ks = 0; ks < 4; ++ks) {
        const int boff = ((t * 4 + ks) * 8 + 2 * w) * 512;
        f16x8 Bh0 = *(const f16x8*)(pgh + boff);
        f16x8 Bh1 = *(const f16x8*)(pgh + boff + 512);
        f16x8 Bl0 = *(const f16x8*)(pgl + boff);
        f16x8 Bl1 = *(const f16x8*)(pgl + boff + 512);
#pragma unroll
        for (int s = 0; s < 2; ++s)
#pragma unroll
          for (int i = 0; i < 3; ++i) {
            f16x8 Ah = *(const f16x8*)(xg_hi + s * 8704 + gA[i] + gtap + ks * 32);
            f16x8 Al = *(const f16x8*)(xg_lo + s * 8704 + gA[i] + gtap + ks * 32);
            Cg[s][i][0] = __builtin_amdgcn_mfma_f32_16x16x32_f16(Ah, Bh0, Cg[s][i][0], 0, 0, 0);
            Cg[s][i][1] = __builtin_amdgcn_mfma_f32_16x16x32_f16(Ah, Bh1, Cg[s][i][1], 0, 0, 0);
            Cg[s][i][0] = __builtin_amdgcn_mfma_f32_16x16x32_f16(Al, Bh0, Cg[s][i][0], 0, 0, 0);
            Cg[s][i][1] = __builtin_amdgcn_mfma_f32_16x16x32_f16(Al, Bh1, Cg[s][i][1], 0, 0, 0);
            Cg[s][i][0] = __builtin_amdgcn_mfma_f32_16x16x32_f16(Ah, Bl0, Cg[s][i][0], 0, 0, 0);
            Cg[s][i][1] = __builtin_amdgcn_mfma_f32_16x16x32_f16(Ah, Bl1, Cg[s][i][1], 0, 0, 0);
          }
      }
    }
    __syncthreads();   // all xg_lo reads done; h overlays xlo
#pragma unroll
    for (int s = 0; s < 2; ++s) {
      float* hb = (float*)(smem + 34816 + s * 18432);
#pragma unroll
      for (int i = 0; i < 3; ++i)
#pragma unroll
        for (int nn = 0; nn < 2; ++nn) {
          const int co_ = (2 * w + nn) * 16 + lr;
#pragma unroll
          for (int j = 0; j < 4; ++j) {
            int pix = i * 16 + lq * 4 + j;
            if (pix < 36) hb[co_ * 36 + pix] = fmaxf(Cg[s][i][nn][j], 0.f);
          }
        }
    }
  }
  __syncthreads();

  // ---- maxpool 2x2 (reg-staged over h->p overlay) ----
  {
    float pr[2][5];
#pragma unroll
    for (int r = 0; r < 5; ++r) {
      int i = tid + 256 * r;
      if (i < 1152) {
        int co_ = i / 9, q = i % 9, py = q / 3, px = q % 3;
#pragma unroll
        for (int s = 0; s < 2; ++s) {
          const float* hp = (const float*)(smem + 34816 + s * 18432)
                            + co_ * 36 + (2 * py) * 6 + 2 * px;
          pr[s][r] = fmaxf(fmaxf(hp[0], hp[1]), fmaxf(hp[6], hp[7]));
        }
      }
    }
    __syncthreads();   // all h reads done
#pragma unroll
    for (int r = 0; r < 5; ++r) {
      int i = tid + 256 * r;
      if (i < 1152) {
        ((float*)(smem + 34816))[i] = pr[0][r];
        ((float*)(smem + 39424))[i] = pr[1][r];
      }
    }
  }
  __syncthreads();

  // ---- fc1 (1152 -> 256): phase-split coalesced GEMV, shared weights ----
  {
    const float* pw = pw1t + w * 256 + 4 * lane;
    const float* p0 = (const float*)(smem + 34816);
    const float* p1 = (const float*)(smem + 39424);
    f32x4 a0 = {0.f, 0.f, 0.f, 0.f}, a1 = {0.f, 0.f, 0.f, 0.f};
#pragma unroll 4
    for (int m = 0; m < 288; ++m) {
      float pv0 = p0[w + 4 * m];                    // wave-uniform broadcast
      float pv1 = p1[w + 4 * m];
      f32x4 wv = *(const f32x4*)(pw + m * 1024);    // coalesced, shared
      a0.x += wv.x * pv0; a0.y += wv.y * pv0; a0.z += wv.z * pv0; a0.w += wv.w * pv0;
      a1.x += wv.x * pv1; a1.y += wv.y * pv1; a1.z += wv.z * pv1; a1.w += wv.w * pv1;
    }
    *(f32x4*)&zred[(0 * 4 + w) * 256 + 4 * lane] = a0;
    *(f32x4*)&zred[(1 * 4 + w) * 256 + 4 * lane] = a1;
  }
  __syncthreads();
  float* z0 = (float*)(smem + 52224);
  float* z1 = (float*)(smem + 53248);
  {
    float fb = fc1_b[tid];
    z0[tid] = fmaxf(zred[tid] + zred[256 + tid] + zred[512 + tid] + zred[768 + tid] + fb, 0.f);
    z1[tid] = fmaxf(zred[1024 + tid] + zred[1280 + tid] + zred[1536 + tid] + zred[1792 + tid] + fb, 0.f);
  }
  __syncthreads();

  // ---- fc2 (256 -> 8), wave-parallel, both samples ----
  if (tid < 128) {
    int s = tid >> 6, l = tid & 63;
    int o = l >> 3, t8 = l & 7;
    const float* zz = s ? z1 : z0;
    const float* wr = fc2_w + o * 256;
    float acc = 0.f;
    for (int k = t8; k < 256; k += 8) acc += zz[k] * wr[k];
    acc += __shfl_xor(acc, 1);
    acc += __shfl_xor(acc, 2);
    acc += __shfl_xor(acc, 4);
    if (t8 == 0) slog[s * 8 + o] = acc + fc2_b[o];
  }
  __syncthreads();

  // ---- top-2 + softmax -> route table (both samples) ----
  if (tid == 0) {
#pragma unroll
    for (int s = 0; s < 2; ++s) {
      const float* sl = slog + s * 8;
      int i0 = 0; float v0 = sl[0];
#pragma unroll
      for (int o = 1; o < 8; ++o) { float v = sl[o]; if (v > v0) { v0 = v; i0 = o; } }
      int i1 = (i0 == 0) ? 1 : 0; float v1 = sl[i1];
#pragma unroll
      for (int o = 0; o < 8; ++o) {
        if (o != i0) { float v = sl[o]; if (v > v1) { v1 = v; i1 = o; } }
      }
      float e1 = expf(v1 - v0);
      float inv = 1.f / (1.f + e1);
      int sb = 2 * b2 + s;
      route_i[2 * sb] = i0; route_i[2 * sb + 1] = i1;
      route_w[2 * sb] = inv; route_w[2 * sb + 1] = e1 * inv;
    }
  }
}

// ---------------------------------------------------------------------------
// Kernel B: experts (R15-verified: RMW out, no facc; strides 136/72 keep
// ds_read_b128 alignment; least spill and fastest measured configuration).
#define ZOFF  4896
#define Y1OFF 5024

#define DECONV_TAP(KY, KX)                                                  \
  {                                                                         \
    constexpr int t_  = (KY) * 3 + (KX);                                    \
    constexpr int dy_ = ((KY) == 2) ? 1 : 0;                                \
    constexpr int dx_ = ((KX) == 2) ? 1 : 0;                                \
    int u0 = uA[0] + dy_, v0 = vA[0] + dx_;                                 \
    int u1 = uA[1] + dy_, v1 = vA[1] + dx_;                                 \
    int u2 = uA[2] + dy_, v2 = vA[2] + dx_;                                 \
    int b0_ = (pvA[0] && u0 < 6 && v0 < 6) ? (u0 * 6 + v0) * 136 : ZOFF;    \
    int b1_ = (pvA[1] && u1 < 6 && v1 < 6) ? (u1 * 6 + v1) * 136 : ZOFF;    \
    int b2_ = (pvA[2] && u2 < 6 && v2 < 6) ? (u2 * 6 + v2) * 136 : ZOFF;    \
    _Pragma("unroll")                                                       \
    for (int ks = 0; ks < 4; ++ks) {                                        \
      f16x8 Bf = *(const f16x8*)(pwd_e + (size_t)(t_ * 4 + ks) * 2048);     \
      f16x8 A0 = *(const f16x8*)(S + b0_ + lq * 8 + ks * 32);               \
      f16x8 A1 = *(const f16x8*)(S + b1_ + lq * 8 + ks * 32);               \
      f16x8 A2 = *(const f16x8*)(S + b2_ + lq * 8 + ks * 32);               \
      Cd0 = __builtin_amdgcn_mfma_f32_16x16x32_f16(A0, Bf, Cd0, 0, 0, 0);   \
      Cd1 = __builtin_amdgcn_mfma_f32_16x16x32_f16(A1, Bf, Cd1, 0, 0, 0);   \
      Cd2 = __builtin_amdgcn_mfma_f32_16x16x32_f16(A2, Bf, Cd2, 0, 0, 0);   \
    }                                                                       \
  }

#define STORE_CLASS(QY, QX)                                                 \
  _Pragma("unroll")                                                         \
  for (int i = 0; i < 3; ++i) {                                             \
    f32x4 Cv = (i == 0) ? Cd0 : ((i == 1) ? Cd1 : Cd2);                     \
    _Pragma("unroll")                                                       \
    for (int j = 0; j < 4; ++j) {                                           \
      int p = i * 16 + lq * 4 + j;                                          \
      if (p < 36) {                                                         \
        int u = p / 6, v = p - 6 * (p / 6);                                 \
        int oy = 2 * u + (QY), ox = 2 * v + (QX);                           \
        S[Y1OFF + ((oy + 1) * 14 + (ox + 1)) * 72 + co] =                   \
            (_Float16)fmaxf(Cv[j], 0.f);                                    \
      }                                                                     \
    }                                                                       \
  }

__global__ __launch_bounds__(256, 4) void cmoe_expert(
    const float* __restrict__ x,
    const float* __restrict__ bd,
    const _Float16* __restrict__ pwd, const _Float16* __restrict__ pwc,
    const float* __restrict__ pbias,
    const int* __restrict__ route_i, const float* __restrict__ route_w,
    float* __restrict__ out)
{
  const int b = blockIdx.x;
  const int tid = threadIdx.x;

  __shared__ __align__(16) char smem[38272];
  _Float16* S = (_Float16*)smem;
  float* sout = (float*)(smem + 10048);   // [72][65] f32, overlays y1

  const int w    = tid >> 6;
  const int lane = tid & 63;
  const int lr   = lane & 15;
  const int lq   = lane >> 4;

  const int e0 = route_i[2 * b], e1 = route_i[2 * b + 1];
  const float w0 = route_w[2 * b], w1 = route_w[2 * b + 1];

  // ---- stage x [36][136] f16 + zero block (ring zeroed per slot) ----
  const float* xb = x + (size_t)b * 4608;
  for (int idx = tid; idx < 4608; idx += 256) {
    int ci = idx / 36, pix = idx - ci * 36;
    S[pix * 136 + ci] = (_Float16)xb[idx];
  }
  if (tid < 128) S[ZOFF + tid] = (_Float16)0.f;

  const int co = w * 16 + lr;

  int uA[3], vA[3], pvA[3];
#pragma unroll
  for (int i = 0; i < 3; ++i) {
    int p = i * 16 + lr;
    pvA[i] = (p < 36);
    int pc = pvA[i] ? p : 0;
    uA[i] = pc / 6; vA[i] = pc - 6 * (pc / 6);
  }
  int cA[9];
#pragma unroll
  for (int mt = 0; mt < 9; ++mt) {
    int pix = mt * 16 + lr;
    int oy = pix / 12, ox = pix - 12 * (pix / 12);
    cA[mt] = Y1OFF + (oy * 14 + ox) * 72 + lq * 8;
  }

  float* ob = out + (size_t)b * 9216;

#pragma unroll 1
  for (int s = 0; s < 2; ++s) {
    const int e = s ? e1 : e0;
    const float wgt = s ? w1 : w0;
    const float db = bd[e * 64 + co];
    const _Float16* pwd_e = pwd + (size_t)e * (9 * 4 * 4 * 512) + w * 512 + lane * 8;

    __syncthreads();   // s=0: x staged; s=1: prev slot's sout reads done

    // ---- y1 zero ring (y1 region overlapped prev sout; safe after barrier) ----
    for (int idx = tid; idx < 52 * 72; idx += 256) {
      int sp = idx / 72, ci = idx % 72;
      int row, col;
      if (sp < 14)      { row = 0;       col = sp; }
      else if (sp < 28) { row = 13;      col = sp - 14; }
      else if (sp < 40) { row = sp - 27; col = 0; }
      else              { row = sp - 39; col = 13; }
      S[Y1OFF + (row * 14 + col) * 72 + ci] = (_Float16)0.f;
    }

    // ---- deconv (parity classes, named regs) ----
    {  // class (qy=1,qx=1)
      f32x4 Cd0 = {db, db, db, db}, Cd1 = Cd0, Cd2 = Cd0;
      DECONV_TAP(0, 0) DECONV_TAP(0, 2) DECONV_TAP(2, 0) DECONV_TAP(2, 2)
      STORE_CLASS(1, 1)
    }
    {  // class (qy=1,qx=0)
      f32x4 Cd0 = {db, db, db, db}, Cd1 = Cd0, Cd2 = Cd0;
      DECONV_TAP(0, 1) DECONV_TAP(2, 1)
      STORE_CLASS(1, 0)
    }
    {  // class (qy=0,qx=1)
      f32x4 Cd0 = {db, db, db, db}, Cd1 = Cd0, Cd2 = Cd0;
      DECONV_TAP(1, 0) DECONV_TAP(1, 2)
      STORE_CLASS(0, 1)
    }
    {  // class (qy=0,qx=0)
      f32x4 Cd0 = {db, db, db, db}, Cd1 = Cd0, Cd2 = Cd0;
      DECONV_TAP(1, 1)
      STORE_CLASS(0, 0)
    }
    __syncthreads();   // y1 complete (ring + data)

    // ---- conv2 (9 tap-GEMMs, K=64), BN folded; scale by wgt in place ----
    f32x4 Cc[9];
    {
      const float cb = pbias[e * 64 + co];
#pragma unroll
      for (int mt = 0; mt < 9; ++mt) Cc[mt] = {cb, cb, cb, cb};
    }
    const _Float16* pwc_e = pwc + (size_t)e * (9 * 2 * 4 * 512) + w * 512 + lane * 8;

#pragma unroll
    for (int t = 0; t < 9; ++t) {
      const int ky = t / 3, kx = t % 3;
      const int aoff = (ky * 14 + kx) * 72;
#pragma unroll
      for (int ks = 0; ks < 2; ++ks) {
        f16x8 Bf = *(const f16x8*)(pwc_e + (size_t)(t * 2 + ks) * 2048);
#pragma unroll
        for (int mt = 0; mt < 9; ++mt) {
          f16x8 Af = *(const f16x8*)(S + cA[mt] + aoff + ks * 32);
          Cc[mt] = __builtin_amdgcn_mfma_f32_16x16x32_f16(Af, Bf, Cc[mt], 0, 0, 0);
        }
      }
    }
#pragma unroll
    for (int mt = 0; mt < 9; ++mt)
#pragma unroll
      for (int j = 0; j < 4; ++j)
        Cc[mt][j] = wgt * fmaxf(Cc[mt][j], 0.f);

    // ---- 2-pass transpose-stage; slot0 stores, slot1 RMW-adds ----
    __syncthreads();   // conv2 y1 reads done; sout overlays y1
#pragma unroll
    for (int mt = 0; mt < 9; ++mt)
#pragma unroll
      for (int j = 0; j < 4; ++j) {
        int pix = mt * 16 + lq * 4 + j;
        if (pix < 72) sout[pix * 65 + co] = Cc[mt][j];
      }
    __syncthreads();
    if (s == 0) {
      for (int j2 = tid; j2 < 4608; j2 += 256) {
        int c2 = j2 / 72, px = j2 - 72 * c2;
        ob[c2 * 144 + px] = sout[px * 65 + c2];
      }
    } else {
      for (int j2 = tid; j2 < 4608; j2 += 256) {
        int c2 = j2 / 72, px = j2 - 72 * c2;
        ob[c2 * 144 + px] += sout[px * 65 + c2];
      }
    }
    __syncthreads();   // sout reads done; restage second half
#pragma unroll
    for (int mt = 0; mt < 9; ++mt)
#pragma unroll
      for (int j = 0; j < 4; ++j) {
        int pix = mt * 16 + lq * 4 + j;
        if (pix >= 72) sout[(pix - 72) * 65 + co] = Cc[mt][j];
      }
    __syncthreads();
    if (s == 0) {
      for (int j2 = tid; j2 < 4608; j2 += 256) {
        int c2 = j2 / 72, px = j2 - 72 * c2;
        ob[c2 * 144 + 72 + px] = sout[px * 65 + c2];
      }
    } else {
      for (int j2 = tid; j2 < 4608; j2 += 256) {
        int c2 = j2 / 72, px = j2 - 72 * c2;
        ob[c2 * 144 + 72 + px] += sout[px * 65 + c2];
      }
    }
    // loop-top barrier orders these sout reads vs next slot's ring writes
  }
}

// ---------------------------------------------------------------------------
// FALLBACK kernel (R1, fp32, known-good) — used when ws_size is too small.

#define DECONV_TAPS(q, ky, r)                                              \
  _Pragma("unroll")                                                        \
  for (int ox = 0; ox < 12; ++ox) {                                        \
    _Pragma("unroll")                                                      \
    for (int kx = 0; kx < 3; ++kx) {                                       \
      const int ss = ox + kx - 1;                                          \
      if (ss >= 0 && ss <= 10 && (ss & 1) == 0)                            \
        dacc[q][ox] += xr[r][ss >> 1] * w9[8 - ((ky) * 3 + (kx))];         \
    }                                                                      \
  }

__global__ __launch_bounds__(256, 2) void cmoe_ref(
    const float* __restrict__ x,
    const float* __restrict__ gw, const float* __restrict__ gb,
    const float* __restrict__ fc1_w, const float* __restrict__ fc1_b,
    const float* __restrict__ fc2_w, const float* __restrict__ fc2_b,
    const float* __restrict__ wd, const float* __restrict__ bd,
    const float* __restrict__ wc, const float* __restrict__ bc,
    const float* __restrict__ bn_g, const float* __restrict__ bn_b,
    const float* __restrict__ bn_m, const float* __restrict__ bn_v,
    float* __restrict__ out)
{
  const int b = blockIdx.x;
  const int tid = threadIdx.x;

  __shared__ float sx[128 * 48];
  __shared__ float sbuf[64 * 168];
  __shared__ int   se[2];
  __shared__ float swv[2];

  const float* xb = x + (size_t)b * 4608;
  for (int i = tid; i < 4608; i += 256) {
    int ci = i / 36, rem = i % 36;
    sx[ci * 48 + 6 + rem] = xb[i];
  }
  for (int i = tid; i < 128 * 12; i += 256) {
    int ci = i / 12, j = i % 12;
    sx[ci * 48 + (j < 6 ? j : 36 + j)] = 0.f;
  }
  __syncthreads();

  {
    const int co = tid >> 1;
    const int hh = tid & 1;
    float hacc[3][6];
    const float bias = gb[co];
#pragma unroll
    for (int q = 0; q < 3; ++q)
#pragma unroll
      for (int ox = 0; ox < 6; ++ox) hacc[q][ox] = bias;

    const float* wbase = gw + co * 1152;
    const float* xsb = sx + hh * 18;
    for (int ci = 0; ci < 128; ++ci) {
      const float* wr = wbase + ci * 9;
      float w9[9];
#pragma unroll
      for (int k = 0; k < 9; ++k) w9[k] = wr[k];
      const float* xr = xsb + ci * 48;
#pragma unroll
      for (int s = 0; s < 5; ++s) {
        float r8[8];
        r8[0] = 0.f; r8[7] = 0.f;
#pragma unroll
        for (int c = 0; c < 6; ++c) r8[c + 1] = xr[s * 6 + c];
#pragma unroll
        for (int ky = 0; ky < 3; ++ky) {
          const int q = s - ky;
          if (q >= 0 && q < 3) {
#pragma unroll
            for (int ox = 0; ox < 6; ++ox)
#pragma unroll
              for (int kx = 0; kx < 3; ++kx)
                hacc[q][ox] += r8[ox + kx] * w9[ky * 3 + kx];
          }
        }
      }
    }
#pragma unroll
    for (int q = 0; q < 3; ++q)
#pragma unroll
      for (int ox = 0; ox < 6; ++ox)
        sbuf[co * 36 + (3 * hh + q) * 6 + ox] = fmaxf(hacc[q][ox], 0.f);
  }
  __syncthreads();

  {
    float* sp = sbuf + 4608;
    for (int i = tid; i < 1152; i += 256) {
      int co = i / 9, r = i % 9, py = r / 3, px = r % 3;
      const float* hp = sbuf + co * 36 + (2 * py) * 6 + 2 * px;
      sp[i] = fmaxf(fmaxf(hp[0], hp[1]), fmaxf(hp[6], hp[7]));
    }
  }
  __syncthreads();

  {
    const float* sp = sbuf + 4608;
    float* sz = sbuf + 5760;
    float acc = fc1_b[tid];
    const float4* wr = (const float4*)(fc1_w + (size_t)tid * 1152);
    const float4* p4 = (const float4*)sp;
#pragma unroll 4
    for (int k = 0; k < 288; ++k) {
      float4 wv4 = wr[k], pv = p4[k];
      acc += wv4.x * pv.x + wv4.y * pv.y + wv4.z * pv.z + wv4.w * pv.w;
    }
    sz[tid] = fmaxf(acc, 0.f);
  }
  __syncthreads();

  {
    const float* sz = sbuf + 5760;
    float* slog = sbuf + 6016;
    if (tid < 8) {
      float acc = fc2_b[tid];
      const float* wr = fc2_w + tid * 256;
      for (int k = 0; k < 256; ++k) acc += sz[k] * wr[k];
      slog[tid] = acc;
    }
  }
  __syncthreads();

  if (tid == 0) {
    const float* slog = sbuf + 6016;
    int i0 = 0; float v0 = slog[0];
#pragma unroll
    for (int o = 1; o < 8; ++o) { float v = slog[o]; if (v > v0) { v0 = v; i0 = o; } }
    int i1 = (i0 == 0) ? 1 : 0; float v1 = slog[i1];
#pragma unroll
    for (int o = 0; o < 8; ++o) {
      if (o != i0) { float v = slog[o]; if (v > v1) { v1 = v; i1 = o; } }
    }
    float e1 = expf(v1 - v0);
    float inv = 1.f / (1.f + e1);
    se[0] = i0; se[1] = i1; swv[0] = inv; swv[1] = e1 * inv;
  }
  __syncthreads();

  for (int i = tid; i < 64 * 24; i += 256) {
    int ci = i / 24, j = i % 24;
    sbuf[ci * 168 + (j < 12 ? j : 144 + j)] = 0.f;
  }

  const int wv = tid >> 6;
  const int co = tid & 63;
  const int iyb = (wv & 1) ? (3 * wv - 1) / 2 : (3 * wv) / 2;

  float facc[3][12];
#pragma unroll
  for (int q = 0; q < 3; ++q)
#pragma unroll
    for (int ox = 0; ox < 12; ++ox) facc[q][ox] = 0.f;

  for (int slot = 0; slot < 2; ++slot) {
    const int e = se[slot];
    const float wgt = swv[slot];

    float dacc[3][12];
    {
      const float db = bd[e * 64 + co];
#pragma unroll
      for (int q = 0; q < 3; ++q)
#pragma unroll
        for (int ox = 0; ox < 12; ++ox) dacc[q][ox] = db;

      const float* wdb = wd + ((size_t)e * 128 * 64 + co) * 9;
      for (int ci = 0; ci < 128; ++ci) {
        const float* wr = wdb + (size_t)ci * 576;
        float w9[9];
#pragma unroll
        for (int k = 0; k < 9; ++k) w9[k] = wr[k];
        float xr[3][6];
#pragma unroll
        for (int r = 0; r < 3; ++r)
#pragma unroll
          for (int c = 0; c < 6; ++c)
            xr[r][c] = sx[ci * 48 + (iyb + r + 1) * 6 + c];
        if (wv & 1) {
          DECONV_TAPS(0, 0, 0)
          DECONV_TAPS(0, 2, 1)
          DECONV_TAPS(1, 1, 1)
          DECONV_TAPS(2, 0, 1)
          DECONV_TAPS(2, 2, 2)
        } else {
          DECONV_TAPS(0, 1, 0)
          DECONV_TAPS(1, 0, 0)
          DECONV_TAPS(1, 2, 1)
          DECONV_TAPS(2, 1, 1)
        }
      }
    }

    __syncthreads();
#pragma unroll
    for (int q = 0; q < 3; ++q)
#pragma unroll
      for (int ox = 0; ox < 12; ++ox)
        sbuf[co * 168 + (3 * wv + q + 1) * 12 + ox] = fmaxf(dacc[q][ox], 0.f);
    __syncthreads();

    float cacc[3][12];
    const float cb = bc[e * 64 + co];
#pragma unroll
    for (int q = 0; q < 3; ++q)
#pragma unroll
      for (int ox = 0; ox < 12; ++ox) cacc[q][ox] = cb;

    const float* wcb = wc + ((size_t)e * 64 + co) * 576;
    for (int ci = 0; ci < 64; ++ci) {
      const float* wr = wcb + ci * 9;
      float w9[9];
#pragma unroll
      for (int k = 0; k < 9; ++k) w9[k] = wr[k];
#pragma unroll
      for (int s = 0; s < 5; ++s) {
        float r14[14];
        r14[0] = 0.f; r14[13] = 0.f;
#pragma unroll
        for (int c = 0; c < 12; ++c) r14[c + 1] = sbuf[ci * 168 + (3 * wv + s) * 12 + c];
#pragma unroll
        for (int ky = 0; ky < 3; ++ky) {
          const int q = s - ky;
          if (q >= 0 && q < 3) {
#pragma unroll
            for (int ox = 0; ox < 12; ++ox)
#pragma unroll
              for (int kx = 0; kx < 3; ++kx)
                cacc[q][ox] += r14[ox + kx] * w9[ky * 3 + kx];
          }
        }
      }
    }

    const float g = bn_g[e * 64 + co], bb = bn_b[e * 64 + co];
    const float mm = bn_m[e * 64 + co], vvv = bn_v[e * 64 + co];
    const float scale = g * rsqrtf(vvv + 1e-5f);
#pragma unroll
    for (int q = 0; q < 3; ++q)
#pragma unroll
      for (int ox = 0; ox < 12; ++ox) {
        float v = (cacc[q][ox] - mm) * scale + bb;
        facc[q][ox] += wgt * fmaxf(v, 0.f);
      }
  }

  float* ob = out + ((size_t)b * 64 + co) * 144;
#pragma unroll
  for (int q = 0; q < 3; ++q)
#pragma unroll
    for (int ox = 0; ox < 12; ++ox)
      ob[(3 * wv + q) * 12 + ox] = facc[q][ox];
}

extern "C" void kernel_launch(void* const* d_in, const int* in_sizes, int n_in,
                              void* d_out, int out_size, void* d_ws, size_t ws_size,
                              hipStream_t stream) {
  const float* x     = (const float*)d_in[0];
  const float* gw    = (const float*)d_in[1];
  const float* gb    = (const float*)d_in[2];
  const float* fc1_w = (const float*)d_in[3];
  const float* fc1_b = (const float*)d_in[4];
  const float* fc2_w = (const float*)d_in[5];
  const float* fc2_b = (const float*)d_in[6];
  const float* wd    = (const float*)d_in[7];
  const float* bd    = (const float*)d_in[8];
  const float* wc    = (const float*)d_in[9];
  const float* bc    = (const float*)d_in[10];
  const float* bn_g  = (const float*)d_in[11];
  const float* bn_b  = (const float*)d_in[12];
  const float* bn_m  = (const float*)d_in[13];
  const float* bn_v  = (const float*)d_in[14];
  float* out = (float*)d_out;

  if (ws_size >= (size_t)WS_NEEDED_BYTES && d_ws != nullptr) {
    _Float16* pwd    = (_Float16*)d_ws;
    _Float16* pwc    = pwd + PWD_ELEMS;
    _Float16* pwg_hi = pwc + PWC_ELEMS;
    _Float16* pwg_lo = pwg_hi + PWG_ELEMS;
    float*    pbias  = (float*)(pwg_lo + PWG_ELEMS);
    int*      route_i = (int*)(pbias + 512);
    float*    route_w = (float*)(route_i + 2048);
    float*    pw1t   = route_w + 2048;

    int total = PWD_ELEMS + PWC_ELEMS + PWG_ELEMS + 512 + PW1T_ELEMS;
    pack_weights<<<dim3((total + 255) / 256), dim3(256), 0, stream>>>(
        wd, wc, gw, fc1_w, bc, bn_g, bn_b, bn_m, bn_v,
        pwd, pwc, pwg_hi, pwg_lo, pbias, pw1t);
    cmoe_gate<<<dim3(512), dim3(256), 0, stream>>>(
        x, gb, pw1t, fc1_b, fc2_w, fc2_b, pwg_hi, pwg_lo, route_i, route_w);
    cmoe_expert<<<dim3(1024), dim3(256), 0, stream>>>(
        x, bd, pwd, pwc, pbias, route_i, route_w, out);
  } else {
    cmoe_ref<<<dim3(1024), dim3(256), 0, stream>>>(
        x, gw, gb, fc1_w, fc1_b, fc2_w, fc2_b,
        wd, bd, wc, bc, bn_g, bn_b, bn_m, bn_v, out);
  }
}

// Round 19
// 154.808 us; speedup vs baseline: 1.1332x; 1.0056x over previous
//
#include <hip/hip_runtime.h>
#include <math.h>

typedef _Float16 f16x8 __attribute__((ext_vector_type(8)));
typedef float    f32x4 __attribute__((ext_vector_type(4)));

// ---------------------------------------------------------------------------
// Workspace layout:
//   pwd    : [8e][9t][4ks][4nt][64l][8] f16 = 589824  (deconv B, kernel-flipped)
//   pwc    : [8e][9t][2ks][4nt][64l][8] f16 = 294912  (conv2 B, BN folded)
//   pwg_hi : [9t][4ks][8nt][64l][8]     f16 = 147456  (gate B, fp16 hi)
//   pwg_lo : [9t][4ks][8nt][64l][8]     f16 = 147456  (gate B, fp16 residual)
//   pbias  : [8e][64]                   f32 = 512
//   route_i: [1024][2] int
//   route_w: [1024][2] f32
//   pw1t   : [1152][256]                f32 = 294912  (fc1_w transposed)
#define PWD_ELEMS 589824
#define PWC_ELEMS 294912
#define PWG_ELEMS 147456
#define PW1T_ELEMS 294912
#define WS_NEEDED_BYTES ((PWD_ELEMS + PWC_ELEMS + 2 * PWG_ELEMS) * 2 + 512 * 4 + 16384 + PW1T_ELEMS * 4)

__global__ void pack_weights(const float* __restrict__ wd,
                             const float* __restrict__ wc,
                             const float* __restrict__ gw,
                             const float* __restrict__ fc1_w,
                             const float* __restrict__ bc,
                             const float* __restrict__ bn_g,
                             const float* __restrict__ bn_b,
                             const float* __restrict__ bn_m,
                             const float* __restrict__ bn_v,
                             _Float16* __restrict__ pwd,
                             _Float16* __restrict__ pwc,
                             _Float16* __restrict__ pwg_hi,
                             _Float16* __restrict__ pwg_lo,
                             float* __restrict__ pbias,
                             float* __restrict__ pw1t)
{
  int i = blockIdx.x * 256 + threadIdx.x;
  if (i < PWD_ELEMS) {
    int j  = i & 7;
    int l  = (i >> 3) & 63;
    int nt = (i >> 9) & 3;
    int ks = (i >> 11) & 3;
    int rest = i >> 13;            // e*9 + t
    int t = rest % 9, e = rest / 9;
    int ky = t / 3, kx = t % 3;
    int k = ks * 32 + (l >> 4) * 8 + j;   // ci 0..127
    int n = nt * 16 + (l & 15);           // co 0..63
    float v = wd[(((size_t)e * 128 + k) * 64 + n) * 9 + (2 - ky) * 3 + (2 - kx)];
    pwd[i] = (_Float16)v;
    return;
  }
  i -= PWD_ELEMS;
  if (i < PWC_ELEMS) {
    int j  = i & 7;
    int l  = (i >> 3) & 63;
    int nt = (i >> 9) & 3;
    int ks = (i >> 11) & 1;
    int rest = i >> 12;            // e*9 + t
    int t = rest % 9, e = rest / 9;
    int ky = t / 3, kx = t % 3;
    int k = ks * 32 + (l >> 4) * 8 + j;   // ci 0..63
    int n = nt * 16 + (l & 15);           // co 0..63
    float scale = bn_g[e * 64 + n] * rsqrtf(bn_v[e * 64 + n] + 1e-5f);
    float v = wc[(((size_t)e * 64 + n) * 64 + k) * 9 + ky * 3 + kx] * scale;
    pwc[i] = (_Float16)v;
    return;
  }
  i -= PWC_ELEMS;
  if (i < PWG_ELEMS) {
    int j  = i & 7;
    int l  = (i >> 3) & 63;
    int nt = (i >> 9) & 7;
    int ks = (i >> 12) & 3;
    int t  = i >> 14;              // 0..8
    int ky = t / 3, kx = t % 3;
    int k = ks * 32 + (l >> 4) * 8 + j;   // ci 0..127
    int n = nt * 16 + (l & 15);           // co 0..127
    float v = gw[(size_t)n * 1152 + k * 9 + ky * 3 + kx];
    _Float16 hi = (_Float16)v;
    pwg_hi[i] = hi;
    pwg_lo[i] = (_Float16)(v - (float)hi);
    return;
  }
  i -= PWG_ELEMS;
  if (i < 512) {
    int e = i >> 6, n = i & 63;
    float scale = bn_g[e * 64 + n] * rsqrtf(bn_v[e * 64 + n] + 1e-5f);
    pbias[i] = (bc[e * 64 + n] - bn_m[e * 64 + n]) * scale + bn_b[e * 64 + n];
    return;
  }
  i -= 512;
  if (i < PW1T_ELEMS) {
    int k = i >> 8, o = i & 255;          // pw1t[k*256 + o] = fc1_w[o][k]
    pw1t[i] = fc1_w[(size_t)o * 1152 + k];
  }
}

// ---------------------------------------------------------------------------
// Kernel A: gate + routing, two samples per block (R13-verified).
__global__ __launch_bounds__(256, 2) void cmoe_gate(
    const float* __restrict__ x, const float* __restrict__ gb,
    const float* __restrict__ pw1t, const float* __restrict__ fc1_b,
    const float* __restrict__ fc2_w, const float* __restrict__ fc2_b,
    const _Float16* __restrict__ pwg_hi, const _Float16* __restrict__ pwg_lo,
    int* __restrict__ route_i, float* __restrict__ route_w)
{
  const int b2 = blockIdx.x;       // sample pair: samples 2*b2, 2*b2+1
  const int tid = threadIdx.x;

  __shared__ __align__(16) char smem[72256];
  _Float16* xg_hi = (_Float16*)smem;               // +s*8704 halfs
  _Float16* xg_lo = (_Float16*)(smem + 34816);     // +s*8704 halfs
  float* zred = (float*)(smem + 44032);            // [2][4][256]
  float* slog = (float*)(smem + 54272);            // [2][8]

  const int w    = tid >> 6;
  const int lane = tid & 63;
  const int lr   = lane & 15;
  const int lq   = lane >> 4;

  // ---- build split-fp16 x with 8x8 halo ring, both samples ----
  for (int idx = tid; idx < 2 * 8192; idx += 256) {
    int s  = idx >> 13;
    int r  = idx & 8191;
    int sp = r >> 7, ci = r & 127;
    int row = sp >> 3, col = sp & 7;
    float v = 0.f;
    if (row >= 1 && row <= 6 && col >= 1 && col <= 6)
      v = x[(size_t)(2 * b2 + s) * 4608 + ci * 36 + (row - 1) * 6 + (col - 1)];
    _Float16 hi = (_Float16)v;
    xg_hi[s * 8704 + sp * 136 + ci] = hi;
    xg_lo[s * 8704 + sp * 136 + ci] = (_Float16)(v - (float)hi);
  }
  __syncthreads();

  int gA[3];
#pragma unroll
  for (int i = 0; i < 3; ++i) {
    int p = i * 16 + lr; if (p >= 36) p = 0;
    int oy = p / 6, ox = p % 6;
    gA[i] = (oy * 8 + ox) * 136 + lq * 8;
  }

  // ---- gate conv3x3, both samples, shared B ----
  {
    f32x4 Cg[2][3][2];
    {
      float b0 = gb[(2 * w) * 16 + lr];
      float b1 = gb[(2 * w + 1) * 16 + lr];
#pragma unroll
      for (int s = 0; s < 2; ++s)
#pragma unroll
        for (int i = 0; i < 3; ++i) {
          Cg[s][i][0] = {b0, b0, b0, b0};
          Cg[s][i][1] = {b1, b1, b1, b1};
        }
    }
    const _Float16* pgh = pwg_hi + lane * 8;
    const _Float16* pgl = pwg_lo + lane * 8;

    for (int t = 0; t < 9; ++t) {
      const int gtap = ((t / 3) * 8 + (t % 3)) * 136;
#pragma unroll
      for (int ks = 0; ks < 4; ++ks) {
        const int boff = ((t * 4 + ks) * 8 + 2 * w) * 512;
        f16x8 Bh0 = *(const f16x8*)(pgh + boff);
        f16x8 Bh1 = *(const f16x8*)(pgh + boff + 512);
        f16x8 Bl0 = *(const f16x8*)(pgl + boff);
        f16x8 Bl1 = *(const f16x8*)(pgl + boff + 512);
#pragma unroll
        for (int s = 0; s < 2; ++s)
#pragma unroll
          for (int i = 0; i < 3; ++i) {
            f16x8 Ah = *(const f16x8*)(xg_hi + s * 8704 + gA[i] + gtap + ks * 32);
            f16x8 Al = *(const f16x8*)(xg_lo + s * 8704 + gA[i] + gtap + ks * 32);
            Cg[s][i][0] = __builtin_amdgcn_mfma_f32_16x16x32_f16(Ah, Bh0, Cg[s][i][0], 0, 0, 0);
            Cg[s][i][1] = __builtin_amdgcn_mfma_f32_16x16x32_f16(Ah, Bh1, Cg[s][i][1], 0, 0, 0);
            Cg[s][i][0] = __builtin_amdgcn_mfma_f32_16x16x32_f16(Al, Bh0, Cg[s][i][0], 0, 0, 0);
            Cg[s][i][1] = __builtin_amdgcn_mfma_f32_16x16x32_f16(Al, Bh1, Cg[s][i][1], 0, 0, 0);
            Cg[s][i][0] = __builtin_amdgcn_mfma_f32_16x16x32_f16(Ah, Bl0, Cg[s][i][0], 0, 0, 0);
            Cg[s][i][1] = __builtin_amdgcn_mfma_f32_16x16x32_f16(Ah, Bl1, Cg[s][i][1], 0, 0, 0);
          }
      }
    }
    __syncthreads();   // all xg_lo reads done; h overlays xlo
#pragma unroll
    for (int s = 0; s < 2; ++s) {
      float* hb = (float*)(smem + 34816 + s * 18432);
#pragma unroll
      for (int i = 0; i < 3; ++i)
#pragma unroll
        for (int nn = 0; nn < 2; ++nn) {
          const int co_ = (2 * w + nn) * 16 + lr;
#pragma unroll
          for (int j = 0; j < 4; ++j) {
            int pix = i * 16 + lq * 4 + j;
            if (pix < 36) hb[co_ * 36 + pix] = fmaxf(Cg[s][i][nn][j], 0.f);
          }
        }
    }
  }
  __syncthreads();

  // ---- maxpool 2x2 (reg-staged over h->p overlay) ----
  {
    float pr[2][5];
#pragma unroll
    for (int r = 0; r < 5; ++r) {
      int i = tid + 256 * r;
      if (i < 1152) {
        int co_ = i / 9, q = i % 9, py = q / 3, px = q % 3;
#pragma unroll
        for (int s = 0; s < 2; ++s) {
          const float* hp = (const float*)(smem + 34816 + s * 18432)
                            + co_ * 36 + (2 * py) * 6 + 2 * px;
          pr[s][r] = fmaxf(fmaxf(hp[0], hp[1]), fmaxf(hp[6], hp[7]));
        }
      }
    }
    __syncthreads();   // all h reads done
#pragma unroll
    for (int r = 0; r < 5; ++r) {
      int i = tid + 256 * r;
      if (i < 1152) {
        ((float*)(smem + 34816))[i] = pr[0][r];
        ((float*)(smem + 39424))[i] = pr[1][r];
      }
    }
  }
  __syncthreads();

  // ---- fc1 (1152 -> 256): phase-split coalesced GEMV, shared weights ----
  {
    const float* pw = pw1t + w * 256 + 4 * lane;
    const float* p0 = (const float*)(smem + 34816);
    const float* p1 = (const float*)(smem + 39424);
    f32x4 a0 = {0.f, 0.f, 0.f, 0.f}, a1 = {0.f, 0.f, 0.f, 0.f};
#pragma unroll 4
    for (int m = 0; m < 288; ++m) {
      float pv0 = p0[w + 4 * m];                    // wave-uniform broadcast
      float pv1 = p1[w + 4 * m];
      f32x4 wv = *(const f32x4*)(pw + m * 1024);    // coalesced, shared
      a0.x += wv.x * pv0; a0.y += wv.y * pv0; a0.z += wv.z * pv0; a0.w += wv.w * pv0;
      a1.x += wv.x * pv1; a1.y += wv.y * pv1; a1.z += wv.z * pv1; a1.w += wv.w * pv1;
    }
    *(f32x4*)&zred[(0 * 4 + w) * 256 + 4 * lane] = a0;
    *(f32x4*)&zred[(1 * 4 + w) * 256 + 4 * lane] = a1;
  }
  __syncthreads();
  float* z0 = (float*)(smem + 52224);
  float* z1 = (float*)(smem + 53248);
  {
    float fb = fc1_b[tid];
    z0[tid] = fmaxf(zred[tid] + zred[256 + tid] + zred[512 + tid] + zred[768 + tid] + fb, 0.f);
    z1[tid] = fmaxf(zred[1024 + tid] + zred[1280 + tid] + zred[1536 + tid] + zred[1792 + tid] + fb, 0.f);
  }
  __syncthreads();

  // ---- fc2 (256 -> 8), wave-parallel, both samples ----
  if (tid < 128) {
    int s = tid >> 6, l = tid & 63;
    int o = l >> 3, t8 = l & 7;
    const float* zz = s ? z1 : z0;
    const float* wr = fc2_w + o * 256;
    float acc = 0.f;
    for (int k = t8; k < 256; k += 8) acc += zz[k] * wr[k];
    acc += __shfl_xor(acc, 1);
    acc += __shfl_xor(acc, 2);
    acc += __shfl_xor(acc, 4);
    if (t8 == 0) slog[s * 8 + o] = acc + fc2_b[o];
  }
  __syncthreads();

  // ---- top-2 + softmax -> route table (both samples) ----
  if (tid == 0) {
#pragma unroll
    for (int s = 0; s < 2; ++s) {
      const float* sl = slog + s * 8;
      int i0 = 0; float v0 = sl[0];
#pragma unroll
      for (int o = 1; o < 8; ++o) { float v = sl[o]; if (v > v0) { v0 = v; i0 = o; } }
      int i1 = (i0 == 0) ? 1 : 0; float v1 = sl[i1];
#pragma unroll
      for (int o = 0; o < 8; ++o) {
        if (o != i0) { float v = sl[o]; if (v > v1) { v1 = v; i1 = o; } }
      }
      float e1 = expf(v1 - v0);
      float inv = 1.f / (1.f + e1);
      int sb = 2 * b2 + s;
      route_i[2 * sb] = i0; route_i[2 * sb + 1] = i1;
      route_w[2 * sb] = inv; route_w[2 * sb + 1] = e1 * inv;
    }
  }
}

// ---------------------------------------------------------------------------
// Kernel B: experts (R15-verified: RMW out, no facc; strides 136/72 keep
// ds_read_b128 alignment; least spill and fastest measured configuration).
#define ZOFF  4896
#define Y1OFF 5024

#define DECONV_TAP(KY, KX)                                                  \
  {                                                                         \
    constexpr int t_  = (KY) * 3 + (KX);                                    \
    constexpr int dy_ = ((KY) == 2) ? 1 : 0;                                \
    constexpr int dx_ = ((KX) == 2) ? 1 : 0;                                \
    int u0 = uA[0] + dy_, v0 = vA[0] + dx_;                                 \
    int u1 = uA[1] + dy_, v1 = vA[1] + dx_;                                 \
    int u2 = uA[2] + dy_, v2 = vA[2] + dx_;                                 \
    int b0_ = (pvA[0] && u0 < 6 && v0 < 6) ? (u0 * 6 + v0) * 136 : ZOFF;    \
    int b1_ = (pvA[1] && u1 < 6 && v1 < 6) ? (u1 * 6 + v1) * 136 : ZOFF;    \
    int b2_ = (pvA[2] && u2 < 6 && v2 < 6) ? (u2 * 6 + v2) * 136 : ZOFF;    \
    _Pragma("unroll")                                                       \
    for (int ks = 0; ks < 4; ++ks) {                                        \
      f16x8 Bf = *(const f16x8*)(pwd_e + (size_t)(t_ * 4 + ks) * 2048);     \
      f16x8 A0 = *(const f16x8*)(S + b0_ + lq * 8 + ks * 32);               \
      f16x8 A1 = *(const f16x8*)(S + b1_ + lq * 8 + ks * 32);               \
      f16x8 A2 = *(const f16x8*)(S + b2_ + lq * 8 + ks * 32);               \
      Cd0 = __builtin_amdgcn_mfma_f32_16x16x32_f16(A0, Bf, Cd0, 0, 0, 0);   \
      Cd1 = __builtin_amdgcn_mfma_f32_16x16x32_f16(A1, Bf, Cd1, 0, 0, 0);   \
      Cd2 = __builtin_amdgcn_mfma_f32_16x16x32_f16(A2, Bf, Cd2, 0, 0, 0);   \
    }                                                                       \
  }

#define STORE_CLASS(QY, QX)                                                 \
  _Pragma("unroll")                                                         \
  for (int i = 0; i < 3; ++i) {                                             \
    f32x4 Cv = (i == 0) ? Cd0 : ((i == 1) ? Cd1 : Cd2);                     \
    _Pragma("unroll")                                                       \
    for (int j = 0; j < 4; ++j) {                                           \
      int p = i * 16 + lq * 4 + j;                                          \
      if (p < 36) {                                                         \
        int u = p / 6, v = p - 6 * (p / 6);                                 \
        int oy = 2 * u + (QY), ox = 2 * v + (QX);                           \
        S[Y1OFF + ((oy + 1) * 14 + (ox + 1)) * 72 + co] =                   \
            (_Float16)fmaxf(Cv[j], 0.f);                                    \
      }                                                                     \
    }                                                                       \
  }

__global__ __launch_bounds__(256, 4) void cmoe_expert(
    const float* __restrict__ x,
    const float* __restrict__ bd,
    const _Float16* __restrict__ pwd, const _Float16* __restrict__ pwc,
    const float* __restrict__ pbias,
    const int* __restrict__ route_i, const float* __restrict__ route_w,
    float* __restrict__ out)
{
  const int b = blockIdx.x;
  const int tid = threadIdx.x;

  __shared__ __align__(16) char smem[38272];
  _Float16* S = (_Float16*)smem;
  float* sout = (float*)(smem + 10048);   // [72][65] f32, overlays y1

  const int w    = tid >> 6;
  const int lane = tid & 63;
  const int lr   = lane & 15;
  const int lq   = lane >> 4;

  const int e0 = route_i[2 * b], e1 = route_i[2 * b + 1];
  const float w0 = route_w[2 * b], w1 = route_w[2 * b + 1];

  // ---- stage x [36][136] f16 + zero block (ring zeroed per slot) ----
  const float* xb = x + (size_t)b * 4608;
  for (int idx = tid; idx < 4608; idx += 256) {
    int ci = idx / 36, pix = idx - ci * 36;
    S[pix * 136 + ci] = (_Float16)xb[idx];
  }
  if (tid < 128) S[ZOFF + tid] = (_Float16)0.f;

  const int co = w * 16 + lr;

  int uA[3], vA[3], pvA[3];
#pragma unroll
  for (int i = 0; i < 3; ++i) {
    int p = i * 16 + lr;
    pvA[i] = (p < 36);
    int pc = pvA[i] ? p : 0;
    uA[i] = pc / 6; vA[i] = pc - 6 * (pc / 6);
  }
  int cA[9];
#pragma unroll
  for (int mt = 0; mt < 9; ++mt) {
    int pix = mt * 16 + lr;
    int oy = pix / 12, ox = pix - 12 * (pix / 12);
    cA[mt] = Y1OFF + (oy * 14 + ox) * 72 + lq * 8;
  }

  float* ob = out + (size_t)b * 9216;

#pragma unroll 1
  for (int s = 0; s < 2; ++s) {
    const int e = s ? e1 : e0;
    const float wgt = s ? w1 : w0;
    const float db = bd[e * 64 + co];
    const _Float16* pwd_e = pwd + (size_t)e * (9 * 4 * 4 * 512) + w * 512 + lane * 8;

    __syncthreads();   // s=0: x staged; s=1: prev slot's sout reads done

    // ---- y1 zero ring (y1 region overlapped prev sout; safe after barrier) ----
    for (int idx = tid; idx < 52 * 72; idx += 256) {
      int sp = idx / 72, ci = idx % 72;
      int row, col;
      if (sp < 14)      { row = 0;       col = sp; }
      else if (sp < 28) { row = 13;      col = sp - 14; }
      else if (sp < 40) { row = sp - 27; col = 0; }
      else              { row = sp - 39; col = 13; }
      S[Y1OFF + (row * 14 + col) * 72 + ci] = (_Float16)0.f;
    }

    // ---- deconv (parity classes, named regs) ----
    {  // class (qy=1,qx=1)
      f32x4 Cd0 = {db, db, db, db}, Cd1 = Cd0, Cd2 = Cd0;
      DECONV_TAP(0, 0) DECONV_TAP(0, 2) DECONV_TAP(2, 0) DECONV_TAP(2, 2)
      STORE_CLASS(1, 1)
    }
    {  // class (qy=1,qx=0)
      f32x4 Cd0 = {db, db, db, db}, Cd1 = Cd0, Cd2 = Cd0;
      DECONV_TAP(0, 1) DECONV_TAP(2, 1)
      STORE_CLASS(1, 0)
    }
    {  // class (qy=0,qx=1)
      f32x4 Cd0 = {db, db, db, db}, Cd1 = Cd0, Cd2 = Cd0;
      DECONV_TAP(1, 0) DECONV_TAP(1, 2)
      STORE_CLASS(0, 1)
    }
    {  // class (qy=0,qx=0)
      f32x4 Cd0 = {db, db, db, db}, Cd1 = Cd0, Cd2 = Cd0;
      DECONV_TAP(1, 1)
      STORE_CLASS(0, 0)
    }
    __syncthreads();   // y1 complete (ring + data)

    // ---- conv2 (9 tap-GEMMs, K=64), BN folded; scale by wgt in place ----
    f32x4 Cc[9];
    {
      const float cb = pbias[e * 64 + co];
#pragma unroll
      for (int mt = 0; mt < 9; ++mt) Cc[mt] = {cb, cb, cb, cb};
    }
    const _Float16* pwc_e = pwc + (size_t)e * (9 * 2 * 4 * 512) + w * 512 + lane * 8;

#pragma unroll
    for (int t = 0; t < 9; ++t) {
      const int ky = t / 3, kx = t % 3;
      const int aoff = (ky * 14 + kx) * 72;
#pragma unroll
      for (int ks = 0; ks < 2; ++ks) {
        f16x8 Bf = *(const f16x8*)(pwc_e + (size_t)(t * 2 + ks) * 2048);
#pragma unroll
        for (int mt = 0; mt < 9; ++mt) {
          f16x8 Af = *(const f16x8*)(S + cA[mt] + aoff + ks * 32);
          Cc[mt] = __builtin_amdgcn_mfma_f32_16x16x32_f16(Af, Bf, Cc[mt], 0, 0, 0);
        }
      }
    }
#pragma unroll
    for (int mt = 0; mt < 9; ++mt)
#pragma unroll
      for (int j = 0; j < 4; ++j)
        Cc[mt][j] = wgt * fmaxf(Cc[mt][j], 0.f);

    // ---- 2-pass transpose-stage; slot0 stores, slot1 RMW-adds ----
    __syncthreads();   // conv2 y1 reads done; sout overlays y1
#pragma unroll
    for (int mt = 0; mt < 9; ++mt)
#pragma unroll
      for (int j = 0; j < 4; ++j) {
        int pix = mt * 16 + lq * 4 + j;
        if (pix < 72) sout[pix * 65 + co] = Cc[mt][j];
      }
    __syncthreads();
    if (s == 0) {
      for (int j2 = tid; j2 < 4608; j2 += 256) {
        int c2 = j2 / 72, px = j2 - 72 * c2;
        ob[c2 * 144 + px] = sout[px * 65 + c2];
      }
    } else {
      for (int j2 = tid; j2 < 4608; j2 += 256) {
        int c2 = j2 / 72, px = j2 - 72 * c2;
        ob[c2 * 144 + px] += sout[px * 65 + c2];
      }
    }
    __syncthreads();   // sout reads done; restage second half
#pragma unroll
    for (int mt = 0; mt < 9; ++mt)
#pragma unroll
      for (int j = 0; j < 4; ++j) {
        int pix = mt * 16 + lq * 4 + j;
        if (pix >= 72) sout[(pix - 72) * 65 + co] = Cc[mt][j];
      }
    __syncthreads();
    if (s == 0) {
      for (int j2 = tid; j2 < 4608; j2 += 256) {
        int c2 = j2 / 72, px = j2 - 72 * c2;
        ob[c2 * 144 + 72 + px] = sout[px * 65 + c2];
      }
    } else {
      for (int j2 = tid; j2 < 4608; j2 += 256) {
        int c2 = j2 / 72, px = j2 - 72 * c2;
        ob[c2 * 144 + 72 + px] += sout[px * 65 + c2];
      }
    }
    // loop-top barrier orders these sout reads vs next slot's ring writes
  }
}

// ---------------------------------------------------------------------------
// FALLBACK kernel (R1, fp32, known-good) — used when ws_size is too small.

#define DECONV_TAPS(q, ky, r)                                              \
  _Pragma("unroll")                                                        \
  for (int ox = 0; ox < 12; ++ox) {                                        \
    _Pragma("unroll")                                                      \
    for (int kx = 0; kx < 3; ++kx) {                                       \
      const int ss = ox + kx - 1;                                          \
      if (ss >= 0 && ss <= 10 && (ss & 1) == 0)                            \
        dacc[q][ox] += xr[r][ss >> 1] * w9[8 - ((ky) * 3 + (kx))];         \
    }                                                                      \
  }

__global__ __launch_bounds__(256, 2) void cmoe_ref(
    const float* __restrict__ x,
    const float* __restrict__ gw, const float* __restrict__ gb,
    const float* __restrict__ fc1_w, const float* __restrict__ fc1_b,
    const float* __restrict__ fc2_w, const float* __restrict__ fc2_b,
    const float* __restrict__ wd, const float* __restrict__ bd,
    const float* __restrict__ wc, const float* __restrict__ bc,
    const float* __restrict__ bn_g, const float* __restrict__ bn_b,
    const float* __restrict__ bn_m, const float* __restrict__ bn_v,
    float* __restrict__ out)
{
  const int b = blockIdx.x;
  const int tid = threadIdx.x;

  __shared__ float sx[128 * 48];
  __shared__ float sbuf[64 * 168];
  __shared__ int   se[2];
  __shared__ float swv[2];

  const float* xb = x + (size_t)b * 4608;
  for (int i = tid; i < 4608; i += 256) {
    int ci = i / 36, rem = i % 36;
    sx[ci * 48 + 6 + rem] = xb[i];
  }
  for (int i = tid; i < 128 * 12; i += 256) {
    int ci = i / 12, j = i % 12;
    sx[ci * 48 + (j < 6 ? j : 36 + j)] = 0.f;
  }
  __syncthreads();

  {
    const int co = tid >> 1;
    const int hh = tid & 1;
    float hacc[3][6];
    const float bias = gb[co];
#pragma unroll
    for (int q = 0; q < 3; ++q)
#pragma unroll
      for (int ox = 0; ox < 6; ++ox) hacc[q][ox] = bias;

    const float* wbase = gw + co * 1152;
    const float* xsb = sx + hh * 18;
    for (int ci = 0; ci < 128; ++ci) {
      const float* wr = wbase + ci * 9;
      float w9[9];
#pragma unroll
      for (int k = 0; k < 9; ++k) w9[k] = wr[k];
      const float* xr = xsb + ci * 48;
#pragma unroll
      for (int s = 0; s < 5; ++s) {
        float r8[8];
        r8[0] = 0.f; r8[7] = 0.f;
#pragma unroll
        for (int c = 0; c < 6; ++c) r8[c + 1] = xr[s * 6 + c];
#pragma unroll
        for (int ky = 0; ky < 3; ++ky) {
          const int q = s - ky;
          if (q >= 0 && q < 3) {
#pragma unroll
            for (int ox = 0; ox < 6; ++ox)
#pragma unroll
              for (int kx = 0; kx < 3; ++kx)
                hacc[q][ox] += r8[ox + kx] * w9[ky * 3 + kx];
          }
        }
      }
    }
#pragma unroll
    for (int q = 0; q < 3; ++q)
#pragma unroll
      for (int ox = 0; ox < 6; ++ox)
        sbuf[co * 36 + (3 * hh + q) * 6 + ox] = fmaxf(hacc[q][ox], 0.f);
  }
  __syncthreads();

  {
    float* sp = sbuf + 4608;
    for (int i = tid; i < 1152; i += 256) {
      int co = i / 9, r = i % 9, py = r / 3, px = r % 3;
      const float* hp = sbuf + co * 36 + (2 * py) * 6 + 2 * px;
      sp[i] = fmaxf(fmaxf(hp[0], hp[1]), fmaxf(hp[6], hp[7]));
    }
  }
  __syncthreads();

  {
    const float* sp = sbuf + 4608;
    float* sz = sbuf + 5760;
    float acc = fc1_b[tid];
    const float4* wr = (const float4*)(fc1_w + (size_t)tid * 1152);
    const float4* p4 = (const float4*)sp;
#pragma unroll 4
    for (int k = 0; k < 288; ++k) {
      float4 wv4 = wr[k], pv = p4[k];
      acc += wv4.x * pv.x + wv4.y * pv.y + wv4.z * pv.z + wv4.w * pv.w;
    }
    sz[tid] = fmaxf(acc, 0.f);
  }
  __syncthreads();

  {
    const float* sz = sbuf + 5760;
    float* slog = sbuf + 6016;
    if (tid < 8) {
      float acc = fc2_b[tid];
      const float* wr = fc2_w + tid * 256;
      for (int k = 0; k < 256; ++k) acc += sz[k] * wr[k];
      slog[tid] = acc;
    }
  }
  __syncthreads();

  if (tid == 0) {
    const float* slog = sbuf + 6016;
    int i0 = 0; float v0 = slog[0];
#pragma unroll
    for (int o = 1; o < 8; ++o) { float v = slog[o]; if (v > v0) { v0 = v; i0 = o; } }
    int i1 = (i0 == 0) ? 1 : 0; float v1 = slog[i1];
#pragma unroll
    for (int o = 0; o < 8; ++o) {
      if (o != i0) { float v = slog[o]; if (v > v1) { v1 = v; i1 = o; } }
    }
    float e1 = expf(v1 - v0);
    float inv = 1.f / (1.f + e1);
    se[0] = i0; se[1] = i1; swv[0] = inv; swv[1] = e1 * inv;
  }
  __syncthreads();

  for (int i = tid; i < 64 * 24; i += 256) {
    int ci = i / 24, j = i % 24;
    sbuf[ci * 168 + (j < 12 ? j : 144 + j)] = 0.f;
  }

  const int wv = tid >> 6;
  const int co = tid & 63;
  const int iyb = (wv & 1) ? (3 * wv - 1) / 2 : (3 * wv) / 2;

  float facc[3][12];
#pragma unroll
  for (int q = 0; q < 3; ++q)
#pragma unroll
    for (int ox = 0; ox < 12; ++ox) facc[q][ox] = 0.f;

  for (int slot = 0; slot < 2; ++slot) {
    const int e = se[slot];
    const float wgt = swv[slot];

    float dacc[3][12];
    {
      const float db = bd[e * 64 + co];
#pragma unroll
      for (int q = 0; q < 3; ++q)
#pragma unroll
        for (int ox = 0; ox < 12; ++ox) dacc[q][ox] = db;

      const float* wdb = wd + ((size_t)e * 128 * 64 + co) * 9;
      for (int ci = 0; ci < 128; ++ci) {
        const float* wr = wdb + (size_t)ci * 576;
        float w9[9];
#pragma unroll
        for (int k = 0; k < 9; ++k) w9[k] = wr[k];
        float xr[3][6];
#pragma unroll
        for (int r = 0; r < 3; ++r)
#pragma unroll
          for (int c = 0; c < 6; ++c)
            xr[r][c] = sx[ci * 48 + (iyb + r + 1) * 6 + c];
        if (wv & 1) {
          DECONV_TAPS(0, 0, 0)
          DECONV_TAPS(0, 2, 1)
          DECONV_TAPS(1, 1, 1)
          DECONV_TAPS(2, 0, 1)
          DECONV_TAPS(2, 2, 2)
        } else {
          DECONV_TAPS(0, 1, 0)
          DECONV_TAPS(1, 0, 0)
          DECONV_TAPS(1, 2, 1)
          DECONV_TAPS(2, 1, 1)
        }
      }
    }

    __syncthreads();
#pragma unroll
    for (int q = 0; q < 3; ++q)
#pragma unroll
      for (int ox = 0; ox < 12; ++ox)
        sbuf[co * 168 + (3 * wv + q + 1) * 12 + ox] = fmaxf(dacc[q][ox], 0.f);
    __syncthreads();

    float cacc[3][12];
    const float cb = bc[e * 64 + co];
#pragma unroll
    for (int q = 0; q < 3; ++q)
#pragma unroll
      for (int ox = 0; ox < 12; ++ox) cacc[q][ox] = cb;

    const float* wcb = wc + ((size_t)e * 64 + co) * 576;
    for (int ci = 0; ci < 64; ++ci) {
      const float* wr = wcb + ci * 9;
      float w9[9];
#pragma unroll
      for (int k = 0; k < 9; ++k) w9[k] = wr[k];
#pragma unroll
      for (int s = 0; s < 5; ++s) {
        float r14[14];
        r14[0] = 0.f; r14[13] = 0.f;
#pragma unroll
        for (int c = 0; c < 12; ++c) r14[c + 1] = sbuf[ci * 168 + (3 * wv + s) * 12 + c];
#pragma unroll
        for (int ky = 0; ky < 3; ++ky) {
          const int q = s - ky;
          if (q >= 0 && q < 3) {
#pragma unroll
            for (int ox = 0; ox < 12; ++ox)
#pragma unroll
              for (int kx = 0; kx < 3; ++kx)
                cacc[q][ox] += r14[ox + kx] * w9[ky * 3 + kx];
          }
        }
      }
    }

    const float g = bn_g[e * 64 + co], bb = bn_b[e * 64 + co];
    const float mm = bn_m[e * 64 + co], vvv = bn_v[e * 64 + co];
    const float scale = g * rsqrtf(vvv + 1e-5f);
#pragma unroll
    for (int q = 0; q < 3; ++q)
#pragma unroll
      for (int ox = 0; ox < 12; ++ox) {
        float v = (cacc[q][ox] - mm) * scale + bb;
        facc[q][ox] += wgt * fmaxf(v, 0.f);
      }
  }

  float* ob = out + ((size_t)b * 64 + co) * 144;
#pragma unroll
  for (int q = 0; q < 3; ++q)
#pragma unroll
    for (int ox = 0; ox < 12; ++ox)
      ob[(3 * wv + q) * 12 + ox] = facc[q][ox];
}

extern "C" void kernel_launch(void* const* d_in, const int* in_sizes, int n_in,
                              void* d_out, int out_size, void* d_ws, size_t ws_size,
                              hipStream_t stream) {
  const float* x     = (const float*)d_in[0];
  const float* gw    = (const float*)d_in[1];
  const float* gb    = (const float*)d_in[2];
  const float* fc1_w = (const float*)d_in[3];
  const float* fc1_b = (const float*)d_in[4];
  const float* fc2_w = (const float*)d_in[5];
  const float* fc2_b = (const float*)d_in[6];
  const float* wd    = (const float*)d_in[7];
  const float* bd    = (const float*)d_in[8];
  const float* wc    = (const float*)d_in[9];
  const float* bc    = (const float*)d_in[10];
  const float* bn_g  = (const float*)d_in[11];
  const float* bn_b  = (const float*)d_in[12];
  const float* bn_m  = (const float*)d_in[13];
  const float* bn_v  = (const float*)d_in[14];
  float* out = (float*)d_out;

  if (ws_size >= (size_t)WS_NEEDED_BYTES && d_ws != nullptr) {
    _Float16* pwd    = (_Float16*)d_ws;
    _Float16* pwc    = pwd + PWD_ELEMS;
    _Float16* pwg_hi = pwc + PWC_ELEMS;
    _Float16* pwg_lo = pwg_hi + PWG_ELEMS;
    float*    pbias  = (float*)(pwg_lo + PWG_ELEMS);
    int*      route_i = (int*)(pbias + 512);
    float*    route_w = (float*)(route_i + 2048);
    float*    pw1t   = route_w + 2048;

    int total = PWD_ELEMS + PWC_ELEMS + PWG_ELEMS + 512 + PW1T_ELEMS;
    pack_weights<<<dim3((total + 255) / 256), dim3(256), 0, stream>>>(
        wd, wc, gw, fc1_w, bc, bn_g, bn_b, bn_m, bn_v,
        pwd, pwc, pwg_hi, pwg_lo, pbias, pw1t);
    cmoe_gate<<<dim3(512), dim3(256), 0, stream>>>(
        x, gb, pw1t, fc1_b, fc2_w, fc2_b, pwg_hi, pwg_lo, route_i, route_w);
    cmoe_expert<<<dim3(1024), dim3(256), 0, stream>>>(
        x, bd, pwd, pwc, pbias, route_i, route_w, out);
  } else {
    cmoe_ref<<<dim3(1024), dim3(256), 0, stream>>>(
        x, gw, gb, fc1_w, fc1_b, fc2_w, fc2_b,
        wd, bd, wc, bc, bn_g, bn_b, bn_m, bn_v, out);
  }
}